// Round 5
// baseline (4755.024 us; speedup 1.0000x reference)
//
#include <hip/hip_runtime.h>
#include <math.h>

// Problem constants
#define BB 16
#define NN 8192
#define SS 1024
#define GG 32
#define MTOT (BB*SS*GG)   // 524288
// MLP: 6 -> 64 -> 64 -> 128

struct alignas(16) f4 { float v[4]; };

// ---------------------------------------------------------------------------
// prep: transpose raw weights: w2T[k][o] (64x64), w3T[k][o] (64x128)
// ---------------------------------------------------------------------------
__global__ __launch_bounds__(512) void prep_kernel(const float* __restrict__ w1g,
                                                   const float* __restrict__ w2g,
                                                   float* __restrict__ w2T,
                                                   float* __restrict__ w3T)
{
    const int tid = threadIdx.x;
    for (int i = tid; i < 4096; i += 512) w2T[(i & 63) * 64 + (i >> 6)] = w1g[i];
    for (int i = tid; i < 8192; i += 512) w3T[(i & 63) * 128 + (i >> 6)] = w2g[i];
}

// ---------------------------------------------------------------------------
// FPS: round-2 version (measured 1026 us — best of 3 variants tried).
// One block/batch, 256 thr, 32 pts/thread in regs, coords in LDS, ONE
// barrier per step (double-buffered reduction slots). Exact f32 semantics;
// argmax ties -> lowest index.
// ---------------------------------------------------------------------------
__global__ __launch_bounds__(256) void fps_kernel(const float* __restrict__ xyz,
                                                  float* __restrict__ newxyz)
{
    __shared__ float lx[NN], ly[NN], lz[NN];            // 96 KB
    __shared__ unsigned long long slots[2][4];
    const int b = blockIdx.x;
    const int t = threadIdx.x;
    const int wave = t >> 6, lane = t & 63;
    const float* base = xyz + (size_t)b * NN * 3;

    float px[32], py[32], pz[32], dd[32];
#pragma unroll
    for (int k = 0; k < 32; ++k) {
        const int p = (k << 8) + t;
        const float x = base[p * 3 + 0];
        const float y = base[p * 3 + 1];
        const float z = base[p * 3 + 2];
        px[k] = x; py[k] = y; pz[k] = z; dd[k] = 1e10f;
        lx[p] = x; ly[p] = y; lz[p] = z;
    }
    __syncthreads();

    int far = 0;
    float* outb = newxyz + (size_t)b * SS * 3;
    for (int s = 0; s < SS; ++s) {
        const float cx = lx[far], cy = ly[far], cz = lz[far];
        if (t == 0) {
            outb[s * 3 + 0] = cx;
            outb[s * 3 + 1] = cy;
            outb[s * 3 + 2] = cz;
        }
        unsigned long long best = 0ull;
#pragma unroll
        for (int k = 0; k < 32; ++k) {
            const float dx = __fsub_rn(px[k], cx);
            const float dy = __fsub_rn(py[k], cy);
            const float dz = __fsub_rn(pz[k], cz);
            const float d  = __fadd_rn(__fadd_rn(__fmul_rn(dx, dx), __fmul_rn(dy, dy)),
                                       __fmul_rn(dz, dz));
            const float nd = fminf(dd[k], d);
            dd[k] = nd;
            const unsigned long long key =
                ((unsigned long long)__float_as_uint(nd) << 32) |
                (unsigned long long)(0xFFFFFFFFu - (unsigned)((k << 8) + t));
            best = (key > best) ? key : best;
        }
#pragma unroll
        for (int off = 32; off > 0; off >>= 1) {
            const unsigned long long o = __shfl_xor(best, off);
            best = (o > best) ? o : best;
        }
        if (lane == 0) slots[s & 1][wave] = best;
        __syncthreads();
        unsigned long long g = slots[s & 1][0];
#pragma unroll
        for (int w = 1; w < 4; ++w) {
            const unsigned long long o = slots[s & 1][w];
            g = (o > g) ? o : g;
        }
        far = (int)(0xFFFFFFFFu - (unsigned)(g & 0xFFFFFFFFull));
    }
}

// ---------------------------------------------------------------------------
// ball query + gather + v first/second moments (analytic BN1 stats).
// ---------------------------------------------------------------------------
__global__ __launch_bounds__(256) void ball_gather_kernel(const float* __restrict__ xyz,
                                                          const float* __restrict__ feat,
                                                          const float* __restrict__ newxyz,
                                                          float* __restrict__ v,
                                                          float* __restrict__ part1)
{
    const int wid  = (int)((blockIdx.x * 256 + threadIdx.x) >> 6);
    const int lane = threadIdx.x & 63;
    if (wid >= BB * SS) return;
    const int b = wid >> 10;

    const float cx = newxyz[wid * 3 + 0];
    const float cy = newxyz[wid * 3 + 1];
    const float cz = newxyz[wid * 3 + 2];
    const float* xb = xyz + (size_t)b * NN * 3;
    const float* fb = feat + (size_t)b * NN * 3;
    const size_t mbase = (size_t)wid * GG;

    float mS[6];
    float mP[36];
#pragma unroll
    for (int c = 0; c < 6; ++c) mS[c] = 0.f;
#pragma unroll
    for (int c = 0; c < 36; ++c) mP[c] = 0.f;

    int cnt = 0, firstp = -1;
    for (int base = 0; base < NN && cnt < GG; base += 64) {
        const int p = base + lane;
        const float x = xb[p * 3 + 0], y = xb[p * 3 + 1], z = xb[p * 3 + 2];
        const float dx = __fsub_rn(cx, x);
        const float dy = __fsub_rn(cy, y);
        const float dz = __fsub_rn(cz, z);
        const float d  = __fadd_rn(__fadd_rn(__fmul_rn(dx, dx), __fmul_rn(dy, dy)),
                                   __fmul_rn(dz, dz));
        const bool hit = (d <= 0.04f);
        const unsigned long long m = __ballot(hit);
        if (firstp < 0 && m != 0ull) firstp = base + (int)__builtin_ctzll(m);
        const int pos = cnt + (int)__popcll(m & ((1ull << lane) - 1ull));
        if (hit && pos < GG) {
            const size_t mm = mbase + pos;
            float a[6];
            a[0] = __fsub_rn(x, cx);
            a[1] = __fsub_rn(y, cy);
            a[2] = __fsub_rn(z, cz);
            a[3] = fb[p * 3 + 0];
            a[4] = fb[p * 3 + 1];
            a[5] = fb[p * 3 + 2];
#pragma unroll
            for (int c = 0; c < 6; ++c) {
                v[(size_t)c * MTOT + mm] = a[c];
                mS[c] += a[c];
#pragma unroll
                for (int dch = 0; dch < 6; ++dch)
                    mP[c * 6 + dch] = fmaf(a[c], a[dch], mP[c * 6 + dch]);
            }
        }
        cnt += (int)__popcll(m);
    }
    if (cnt < GG) {
        const int p = firstp;
        const float x = xb[p * 3 + 0], y = xb[p * 3 + 1], z = xb[p * 3 + 2];
        float a[6];
        a[0] = __fsub_rn(x, cx);
        a[1] = __fsub_rn(y, cy);
        a[2] = __fsub_rn(z, cz);
        a[3] = fb[p * 3 + 0];
        a[4] = fb[p * 3 + 1];
        a[5] = fb[p * 3 + 2];
        for (int j = cnt + lane; j < GG; j += 64) {
            const size_t mm = mbase + j;
#pragma unroll
            for (int c = 0; c < 6; ++c) {
                v[(size_t)c * MTOT + mm] = a[c];
                mS[c] += a[c];
#pragma unroll
                for (int dch = 0; dch < 6; ++dch)
                    mP[c * 6 + dch] = fmaf(a[c], a[dch], mP[c * 6 + dch]);
            }
        }
    }
#pragma unroll
    for (int off = 1; off < 64; off <<= 1) {
#pragma unroll
        for (int c = 0; c < 6; ++c) mS[c] += __shfl_xor(mS[c], off);
#pragma unroll
        for (int c = 0; c < 36; ++c) mP[c] += __shfl_xor(mP[c], off);
    }
    if (lane == 0) {
        float* row = part1 + (size_t)wid * 42;
#pragma unroll
        for (int c = 0; c < 6; ++c) row[c] = mS[c];
#pragma unroll
        for (int c = 0; c < 36; ++c) row[6 + c] = mP[c];
    }
}

// ---------------------------------------------------------------------------
// finalize1: analytic BN1 from v moments; fold -> w1S[c][o], c1[o].
// ---------------------------------------------------------------------------
__global__ __launch_bounds__(512) void finalize1_kernel(const float* __restrict__ part1,
                                                        const float* __restrict__ w0,
                                                        const float* __restrict__ g0,
                                                        const float* __restrict__ bt0,
                                                        float* __restrict__ w1S,
                                                        float* __restrict__ c1)
{
    __shared__ double red[504];
    __shared__ double tot[42];
    const int tid = threadIdx.x;
    if (tid < 504) {
        const int j = tid % 42, r = tid / 42;   // 12 reducers per moment
        double s = 0.0;
        for (int i = r; i < BB * SS; i += 12) s += (double)part1[(size_t)i * 42 + j];
        red[tid] = s;
    }
    __syncthreads();
    if (tid < 42) {
        double s = 0.0;
        for (int r = 0; r < 12; ++r) s += red[r * 42 + tid];
        tot[tid] = s / (double)MTOT;
    }
    __syncthreads();
    if (tid < 64) {
        double m1 = 0.0;
        for (int c = 0; c < 6; ++c) m1 += (double)w0[tid * 6 + c] * tot[c];
        double e2 = 0.0;
        for (int c = 0; c < 6; ++c)
            for (int d = 0; d < 6; ++d)
                e2 += (double)w0[tid * 6 + c] * (double)w0[tid * 6 + d] * tot[6 + c * 6 + d];
        double var = e2 - m1 * m1;
        if (var < 0.0) var = 0.0;
        const double A = (double)g0[tid] / sqrt(var + 1e-5);
        c1[tid] = (float)((double)bt0[tid] - A * m1);
        for (int c = 0; c < 6; ++c)
            w1S[c * 64 + tid] = (float)(A * (double)w0[tid * 6 + c]);
    }
}

// ---------------------------------------------------------------------------
// Chain kernel. Lane owns one point. h[64] and acc[64] in REGISTERS (all
// index loops fully unrolled -> static indices, no scratch, no DS dependency
// in the k-loops; weights via wave-uniform s_loads only).
// Stats: 16-channel chunks staged through a 16KB XOR-swizzled LDS buffer
// (idx = r*256 + (c ^ ((r&7)<<2)), 4-way worst case), accumulated in regs
// across tiles, block-reduced once at kernel end.
// PHASE 2: stats of x2_nb. PHASE 3: stats of x3_nb (two sequential 64-ch
// halves) + per-32pt-group MAX of x3_nb -> gmax (BN3+relu+max is monotone,
// A3>0 since g2=ones, so max commutes; applied later by final_out).
// ---------------------------------------------------------------------------
template<int PHASE>
__global__ __launch_bounds__(256, PHASE == 2 ? 3 : 2) void chain_kernel(
    const float* __restrict__ v,
    const float* __restrict__ w1S, const float* __restrict__ c1v,
    const float* __restrict__ w2x, const float* __restrict__ c2v,
    const float* __restrict__ w3x,
    float* __restrict__ part, float* __restrict__ gmax, int tpb)
{
    constexpr int NCH = (PHASE == 2) ? 4 : 8;
    __shared__ float lds[4096];
    const int tid  = threadIdx.x;
    const int lane = tid & 63;
    const int lo16 = tid & 15;
    const int rg   = tid >> 4;
    const int xmask = (lo16 & 7) << 2;

    float sAcc[NCH], qAcc[NCH];
#pragma unroll
    for (int i = 0; i < NCH; ++i) { sAcc[i] = 0.f; qAcc[i] = 0.f; }

    for (int ti = 0; ti < tpb; ++ti) {
        const int tile = blockIdx.x * tpb + ti;
        const int m = tile * 256 + tid;

        // ---- L1 (folded BN1) -> h1 in regs ----
        float h[64];
#pragma unroll
        for (int o = 0; o < 64; ++o) h[o] = c1v[o];
#pragma unroll
        for (int c = 0; c < 6; ++c) {
            const float xv = v[(size_t)c * MTOT + m];
            const float* __restrict__ wr = w1S + c * 64;
#pragma unroll
            for (int o = 0; o < 64; ++o) h[o] = fmaf(wr[o], xv, h[o]);
        }
#pragma unroll
        for (int o = 0; o < 64; ++o) h[o] = fmaxf(h[o], 0.f);

        // ---- L2 ----
        float acc[64];
#pragma unroll
        for (int o = 0; o < 64; ++o) acc[o] = (PHASE == 2) ? 0.f : c2v[o];
#pragma unroll
        for (int k = 0; k < 64; ++k) {
            const float hk = h[k];
            const float* __restrict__ wr = w2x + (k << 6);
#pragma unroll
            for (int o = 0; o < 64; ++o) acc[o] = fmaf(wr[o], hk, acc[o]);
        }

        if constexpr (PHASE == 2) {
#pragma unroll
            for (int ch = 0; ch < 4; ++ch) {
                __syncthreads();
#pragma unroll
                for (int j = 0; j < 16; ++j)
                    lds[j * 256 + (tid ^ ((j & 7) << 2))] = acc[ch * 16 + j];
                __syncthreads();
                float s = 0.f, q = 0.f;
#pragma unroll
                for (int t4i = 0; t4i < 4; ++t4i) {
                    const f4 xv = *reinterpret_cast<const f4*>(
                        &lds[lo16 * 256 + ((rg * 16 + 4 * t4i) ^ xmask)]);
#pragma unroll
                    for (int jj = 0; jj < 4; ++jj) {
                        s += xv.v[jj]; q = fmaf(xv.v[jj], xv.v[jj], q);
                    }
                }
                sAcc[ch] += s; qAcc[ch] += q;
            }
        } else {
            // h <- h2 (folded BN2)
#pragma unroll
            for (int o = 0; o < 64; ++o) h[o] = fmaxf(acc[o], 0.f);

#pragma unroll
            for (int half = 0; half < 2; ++half) {
                // ---- L3 half ----
#pragma unroll
                for (int o = 0; o < 64; ++o) acc[o] = 0.f;
#pragma unroll
                for (int k = 0; k < 64; ++k) {
                    const float hk = h[k];
                    const float* __restrict__ wr = w3x + (k << 7) + (half << 6);
#pragma unroll
                    for (int o = 0; o < 64; ++o) acc[o] = fmaf(wr[o], hk, acc[o]);
                }
                // stats (raw acc)
#pragma unroll
                for (int ch = 0; ch < 4; ++ch) {
                    __syncthreads();
#pragma unroll
                    for (int j = 0; j < 16; ++j)
                        lds[j * 256 + (tid ^ ((j & 7) << 2))] = acc[ch * 16 + j];
                    __syncthreads();
                    float s = 0.f, q = 0.f;
#pragma unroll
                    for (int t4i = 0; t4i < 4; ++t4i) {
                        const f4 xv = *reinterpret_cast<const f4*>(
                            &lds[lo16 * 256 + ((rg * 16 + 4 * t4i) ^ xmask)]);
#pragma unroll
                        for (int jj = 0; jj < 4; ++jj) {
                            s += xv.v[jj]; q = fmaf(xv.v[jj], xv.v[jj], q);
                        }
                    }
                    sAcc[half * 4 + ch] += s; qAcc[half * 4 + ch] += q;
                }
                // group max over the 32-lane group (destroys acc; recomputed
                // from h for half 1)
#pragma unroll
                for (int off = 1; off < 32; off <<= 1) {
#pragma unroll
                    for (int o = 0; o < 64; ++o)
                        acc[o] = fmaxf(acc[o], __shfl_xor(acc[o], off));
                }
                if ((lane & 31) == 0) {
                    const int g = tile * 8 + (tid >> 5);
#pragma unroll
                    for (int og = 0; og < 16; ++og) {
                        f4 t4;
                        t4.v[0] = acc[og * 4 + 0];
                        t4.v[1] = acc[og * 4 + 1];
                        t4.v[2] = acc[og * 4 + 2];
                        t4.v[3] = acc[og * 4 + 3];
                        *reinterpret_cast<f4*>(&gmax[(size_t)g * 128 + (half << 6) + og * 4]) = t4;
                    }
                }
            }
        }
    }

    // ---- block-level reduce of per-thread stat partials ----
#pragma unroll
    for (int ch = 0; ch < NCH; ++ch) {
        __syncthreads();
        lds[tid] = sAcc[ch];
        lds[256 + tid] = qAcc[ch];
        __syncthreads();
        if (tid < 16) {
            float s = 0.f;
#pragma unroll
            for (int r = 0; r < 16; ++r) s += lds[r * 16 + tid];
            part[(size_t)blockIdx.x * (32 * NCH) + ch * 16 + tid] = s;
        } else if (tid < 32) {
            const int lo = tid - 16;
            float q = 0.f;
#pragma unroll
            for (int r = 0; r < 16; ++r) q += lds[256 + r * 16 + lo];
            part[(size_t)blockIdx.x * (32 * NCH) + 16 * NCH + ch * 16 + lo] = q;
        }
    }
}

// ---------------------------------------------------------------------------
// finalize2: reduce chain<2> partials (1024 blocks x [s64|q64]) -> A2/c2,
// fold w2S = A2 o* w2T.
// ---------------------------------------------------------------------------
__global__ __launch_bounds__(512) void finalize2_kernel(const float* __restrict__ part,
                                                        const float* __restrict__ w2T,
                                                        const float* __restrict__ g1,
                                                        const float* __restrict__ bt1,
                                                        float* __restrict__ w2S,
                                                        float* __restrict__ c2)
{
    __shared__ double tot[512];
    __shared__ float As[64];
    const int tid = threadIdx.x;
    const int j = tid & 127, r = tid >> 7;    // 4 reducers per stat
    double s = 0.0;
    for (int blk = r; blk < 1024; blk += 4) s += (double)part[(size_t)blk * 128 + j];
    tot[tid] = s;
    __syncthreads();
    if (tid < 128) {
        const double t = tot[tid] + tot[128 + tid] + tot[256 + tid] + tot[384 + tid];
        tot[tid] = t;
    }
    __syncthreads();
    if (tid < 64) {
        const double mean = tot[tid] / (double)MTOT;
        double var = tot[64 + tid] / (double)MTOT - mean * mean;
        if (var < 0.0) var = 0.0;
        const double A = (double)g1[tid] / sqrt(var + 1e-5);
        As[tid] = (float)A;
        c2[tid] = (float)((double)bt1[tid] - A * mean);
    }
    __syncthreads();
    for (int i = tid; i < 4096; i += 512) w2S[i] = As[i & 63] * w2T[i];
}

// ---------------------------------------------------------------------------
// finalize3: reduce chain<3> partials (1024 blocks x [s128|q128]) -> A3/c3.
// ---------------------------------------------------------------------------
__global__ __launch_bounds__(512) void finalize3_kernel(const float* __restrict__ part,
                                                        const float* __restrict__ g2,
                                                        const float* __restrict__ bt2,
                                                        float* __restrict__ A3,
                                                        float* __restrict__ c3)
{
    __shared__ double tot[512];
    const int tid = threadIdx.x;
    const int j = tid & 255, r = tid >> 8;    // 2 reducers per stat
    double s = 0.0;
    for (int blk = r; blk < 1024; blk += 2) s += (double)part[(size_t)blk * 256 + j];
    tot[tid] = s;
    __syncthreads();
    if (tid < 256) {
        const double t = tot[tid] + tot[256 + tid];
        tot[tid] = t;
    }
    __syncthreads();
    if (tid < 128) {
        const double mean = tot[tid] / (double)MTOT;
        double var = tot[128 + tid] / (double)MTOT - mean * mean;
        if (var < 0.0) var = 0.0;
        const double A = (double)g2[tid] / sqrt(var + 1e-5);
        A3[tid] = (float)A;
        c3[tid] = (float)((double)bt2[tid] - A * mean);
    }
}

// ---------------------------------------------------------------------------
// final_out: in-place out = relu(A3*gmax + c3) over (16384 groups x 128 ch).
// ---------------------------------------------------------------------------
__global__ __launch_bounds__(256) void final_out_kernel(float* __restrict__ outF,
                                                        const float* __restrict__ A3,
                                                        const float* __restrict__ c3)
{
    __shared__ float As[128], Cs[128];
    const int tid = threadIdx.x;
    if (tid < 128) { As[tid] = A3[tid]; Cs[tid] = c3[tid]; }
    __syncthreads();
    const int idx = (int)blockIdx.x * 256 + tid;      // f4 index, total 524288
    f4 val = *reinterpret_cast<f4*>(&outF[(size_t)idx * 4]);
    const int chb = (idx * 4) & 127;
#pragma unroll
    for (int jj = 0; jj < 4; ++jj)
        val.v[jj] = fmaxf(fmaf(As[chb + jj], val.v[jj], Cs[chb + jj]), 0.f);
    *reinterpret_cast<f4*>(&outF[(size_t)idx * 4]) = val;
}

// ---------------------------------------------------------------------------
extern "C" void kernel_launch(void* const* d_in, const int* in_sizes, int n_in,
                              void* d_out, int out_size, void* d_ws, size_t ws_size,
                              hipStream_t stream)
{
    const float* xyz  = (const float*)d_in[0];
    const float* feat = (const float*)d_in[1];
    const float* w0  = (const float*)d_in[2];
    const float* g0  = (const float*)d_in[4];
    const float* bt0 = (const float*)d_in[5];
    const float* w1  = (const float*)d_in[6];
    const float* g1  = (const float*)d_in[8];
    const float* bt1 = (const float*)d_in[9];
    const float* w2  = (const float*)d_in[10];
    const float* g2  = (const float*)d_in[12];
    const float* bt2 = (const float*)d_in[13];

    float* out    = (float*)d_out;
    float* newxyz = out;                 // (16,1024,3)
    float* outF   = out + BB * SS * 3;   // (16,1024,128) — holds gmax then final

    float* wsf  = (float*)d_ws;
    float* v    = wsf;                         // 6*MTOT = 3145728
    float* part = wsf + 6ull * MTOT;           // 688128 (moments / stat partials)
    float* w2T  = part + 688128;               // 4096
    float* w3T  = w2T + 4096;                  // 8192
    float* w1S  = w3T + 8192;                  // 384
    float* w2S  = w1S + 384;                   // 4096
    float* c1   = w2S + 4096;                  // 64
    float* c2   = c1 + 64;                     // 64
    float* A3   = c2 + 64;                     // 128
    float* c3   = A3 + 128;                    // 128

    prep_kernel<<<dim3(1), dim3(512), 0, stream>>>(w1, w2, w2T, w3T);
    fps_kernel<<<dim3(BB), dim3(256), 0, stream>>>(xyz, newxyz);
    ball_gather_kernel<<<dim3(4096), dim3(256), 0, stream>>>(xyz, feat, newxyz, v, part);
    finalize1_kernel<<<dim3(1), dim3(512), 0, stream>>>(part, w0, g0, bt0, w1S, c1);

    chain_kernel<2><<<dim3(1024), dim3(256), 0, stream>>>(v, w1S, c1, w2T, nullptr,
                                                          nullptr, part, nullptr, 2);
    finalize2_kernel<<<dim3(1), dim3(512), 0, stream>>>(part, w2T, g1, bt1, w2S, c2);

    chain_kernel<3><<<dim3(1024), dim3(256), 0, stream>>>(v, w1S, c1, w2S, c2,
                                                          w3T, part, outF, 2);
    finalize3_kernel<<<dim3(1), dim3(512), 0, stream>>>(part, g2, bt2, A3, c3);
    final_out_kernel<<<dim3(2048), dim3(256), 0, stream>>>(outF, A3, c3);
}

// Round 6
// 2009.021 us; speedup vs baseline: 2.3668x; 2.3668x over previous
//
#include <hip/hip_runtime.h>
#include <math.h>

// Problem constants
#define BB 16
#define NN 8192
#define SS 1024
#define GG 32
#define MTOT (BB*SS*GG)   // 524288
// MLP: 6 -> 64 -> 64 -> 128

struct alignas(16) f4 { float v[4]; };

typedef __attribute__((ext_vector_type(8))) short bfrag;   // 8 bf16 = 4 VGPR
typedef __attribute__((ext_vector_type(4))) float facc;    // 4 f32 acc

#define MFMA16(a, b, c) __builtin_amdgcn_mfma_f32_16x16x32_bf16(a, b, c, 0, 0, 0)

__device__ __forceinline__ unsigned short f2bf(float f) {
    const unsigned u = __float_as_uint(f);
    return (unsigned short)((u + 0x7FFFu + ((u >> 16) & 1u)) >> 16);
}
__device__ __forceinline__ unsigned packbf(float lo, float hi) {
    return (unsigned)f2bf(lo) | ((unsigned)f2bf(hi) << 16);
}

// ---------------------------------------------------------------------------
// prep: build RAW bf16 A-frags for W2 (8 frags) and W3 (16 frags).
// Frag layout: entry (f, lane l): A[o][k], o = (f>>1)*16 + (l&15),
// k = (f&1)*32 + (l>>4)*8 + j, j=0..7. Stored flat: [(f*64+l)*8 + j].
// ---------------------------------------------------------------------------
__global__ __launch_bounds__(512) void prep_kernel(const float* __restrict__ w1g,
                                                   const float* __restrict__ w2g,
                                                   short* __restrict__ wf2r,
                                                   short* __restrict__ wf3r)
{
    const int tid = threadIdx.x;
    {
        const int f = tid >> 6, l = tid & 63;
        const int o = (f >> 1) * 16 + (l & 15);
        const int kb = (f & 1) * 32 + (l >> 4) * 8;
#pragma unroll
        for (int j = 0; j < 8; ++j)
            wf2r[tid * 8 + j] = (short)f2bf(w1g[o * 64 + kb + j]);
    }
    for (int idx = tid; idx < 1024; idx += 512) {
        const int f = idx >> 6, l = idx & 63;
        const int o = (f >> 1) * 16 + (l & 15);
        const int kb = (f & 1) * 32 + (l >> 4) * 8;
#pragma unroll
        for (int j = 0; j < 8; ++j)
            wf3r[idx * 8 + j] = (short)f2bf(w2g[o * 64 + kb + j]);
    }
}

// ---------------------------------------------------------------------------
// FPS: round-2 winner (1026 us). One block/batch, 256 thr, 32 pts/thread in
// regs, coords in LDS, one barrier per step. Exact f32; ties -> lowest index.
// ---------------------------------------------------------------------------
__global__ __launch_bounds__(256) void fps_kernel(const float* __restrict__ xyz,
                                                  float* __restrict__ newxyz)
{
    __shared__ float lx[NN], ly[NN], lz[NN];            // 96 KB
    __shared__ unsigned long long slots[2][4];
    const int b = blockIdx.x;
    const int t = threadIdx.x;
    const int wave = t >> 6, lane = t & 63;
    const float* base = xyz + (size_t)b * NN * 3;

    float px[32], py[32], pz[32], dd[32];
#pragma unroll
    for (int k = 0; k < 32; ++k) {
        const int p = (k << 8) + t;
        const float x = base[p * 3 + 0];
        const float y = base[p * 3 + 1];
        const float z = base[p * 3 + 2];
        px[k] = x; py[k] = y; pz[k] = z; dd[k] = 1e10f;
        lx[p] = x; ly[p] = y; lz[p] = z;
    }
    __syncthreads();

    int far = 0;
    float* outb = newxyz + (size_t)b * SS * 3;
    for (int s = 0; s < SS; ++s) {
        const float cx = lx[far], cy = ly[far], cz = lz[far];
        if (t == 0) {
            outb[s * 3 + 0] = cx;
            outb[s * 3 + 1] = cy;
            outb[s * 3 + 2] = cz;
        }
        unsigned long long best = 0ull;
#pragma unroll
        for (int k = 0; k < 32; ++k) {
            const float dx = __fsub_rn(px[k], cx);
            const float dy = __fsub_rn(py[k], cy);
            const float dz = __fsub_rn(pz[k], cz);
            const float d  = __fadd_rn(__fadd_rn(__fmul_rn(dx, dx), __fmul_rn(dy, dy)),
                                       __fmul_rn(dz, dz));
            const float nd = fminf(dd[k], d);
            dd[k] = nd;
            const unsigned long long key =
                ((unsigned long long)__float_as_uint(nd) << 32) |
                (unsigned long long)(0xFFFFFFFFu - (unsigned)((k << 8) + t));
            best = (key > best) ? key : best;
        }
#pragma unroll
        for (int off = 32; off > 0; off >>= 1) {
            const unsigned long long o = __shfl_xor(best, off);
            best = (o > best) ? o : best;
        }
        if (lane == 0) slots[s & 1][wave] = best;
        __syncthreads();
        unsigned long long g = slots[s & 1][0];
#pragma unroll
        for (int w = 1; w < 4; ++w) {
            const unsigned long long o = slots[s & 1][w];
            g = (o > g) ? o : g;
        }
        far = (int)(0xFFFFFFFFu - (unsigned)(g & 0xFFFFFFFFull));
    }
}

// ---------------------------------------------------------------------------
// ball query + gather + v first/second moments (analytic BN1 stats).
// ---------------------------------------------------------------------------
__global__ __launch_bounds__(256) void ball_gather_kernel(const float* __restrict__ xyz,
                                                          const float* __restrict__ feat,
                                                          const float* __restrict__ newxyz,
                                                          float* __restrict__ v,
                                                          float* __restrict__ part1)
{
    const int wid  = (int)((blockIdx.x * 256 + threadIdx.x) >> 6);
    const int lane = threadIdx.x & 63;
    if (wid >= BB * SS) return;
    const int b = wid >> 10;

    const float cx = newxyz[wid * 3 + 0];
    const float cy = newxyz[wid * 3 + 1];
    const float cz = newxyz[wid * 3 + 2];
    const float* xb = xyz + (size_t)b * NN * 3;
    const float* fb = feat + (size_t)b * NN * 3;
    const size_t mbase = (size_t)wid * GG;

    float mS[6];
    float mP[36];
#pragma unroll
    for (int c = 0; c < 6; ++c) mS[c] = 0.f;
#pragma unroll
    for (int c = 0; c < 36; ++c) mP[c] = 0.f;

    int cnt = 0, firstp = -1;
    for (int base = 0; base < NN && cnt < GG; base += 64) {
        const int p = base + lane;
        const float x = xb[p * 3 + 0], y = xb[p * 3 + 1], z = xb[p * 3 + 2];
        const float dx = __fsub_rn(cx, x);
        const float dy = __fsub_rn(cy, y);
        const float dz = __fsub_rn(cz, z);
        const float d  = __fadd_rn(__fadd_rn(__fmul_rn(dx, dx), __fmul_rn(dy, dy)),
                                   __fmul_rn(dz, dz));
        const bool hit = (d <= 0.04f);
        const unsigned long long m = __ballot(hit);
        if (firstp < 0 && m != 0ull) firstp = base + (int)__builtin_ctzll(m);
        const int pos = cnt + (int)__popcll(m & ((1ull << lane) - 1ull));
        if (hit && pos < GG) {
            const size_t mm = mbase + pos;
            float a[6];
            a[0] = __fsub_rn(x, cx);
            a[1] = __fsub_rn(y, cy);
            a[2] = __fsub_rn(z, cz);
            a[3] = fb[p * 3 + 0];
            a[4] = fb[p * 3 + 1];
            a[5] = fb[p * 3 + 2];
#pragma unroll
            for (int c = 0; c < 6; ++c) {
                v[(size_t)c * MTOT + mm] = a[c];
                mS[c] += a[c];
#pragma unroll
                for (int dch = 0; dch < 6; ++dch)
                    mP[c * 6 + dch] = fmaf(a[c], a[dch], mP[c * 6 + dch]);
            }
        }
        cnt += (int)__popcll(m);
    }
    if (cnt < GG) {
        const int p = firstp;
        const float x = xb[p * 3 + 0], y = xb[p * 3 + 1], z = xb[p * 3 + 2];
        float a[6];
        a[0] = __fsub_rn(x, cx);
        a[1] = __fsub_rn(y, cy);
        a[2] = __fsub_rn(z, cz);
        a[3] = fb[p * 3 + 0];
        a[4] = fb[p * 3 + 1];
        a[5] = fb[p * 3 + 2];
        for (int j = cnt + lane; j < GG; j += 64) {
            const size_t mm = mbase + j;
#pragma unroll
            for (int c = 0; c < 6; ++c) {
                v[(size_t)c * MTOT + mm] = a[c];
                mS[c] += a[c];
#pragma unroll
                for (int dch = 0; dch < 6; ++dch)
                    mP[c * 6 + dch] = fmaf(a[c], a[dch], mP[c * 6 + dch]);
            }
        }
    }
#pragma unroll
    for (int off = 1; off < 64; off <<= 1) {
#pragma unroll
        for (int c = 0; c < 6; ++c) mS[c] += __shfl_xor(mS[c], off);
#pragma unroll
        for (int c = 0; c < 36; ++c) mP[c] += __shfl_xor(mP[c], off);
    }
    if (lane == 0) {
        float* row = part1 + (size_t)wid * 42;
#pragma unroll
        for (int c = 0; c < 6; ++c) row[c] = mS[c];
#pragma unroll
        for (int c = 0; c < 36; ++c) row[6 + c] = mP[c];
    }
}

// ---------------------------------------------------------------------------
// finalize1: analytic BN1 from v moments; emit folded bf16 W1 A-frags
// (4 frags; only lanes h==0, j<6 nonzero) and c1[64] (f32).
// ---------------------------------------------------------------------------
__global__ __launch_bounds__(512) void finalize1_kernel(const float* __restrict__ part1,
                                                        const float* __restrict__ w0,
                                                        const float* __restrict__ g0,
                                                        const float* __restrict__ bt0,
                                                        short* __restrict__ wf1,
                                                        float* __restrict__ c1)
{
    __shared__ double red[504];
    __shared__ double tot[42];
    __shared__ float Asf[64];
    const int tid = threadIdx.x;
    if (tid < 504) {
        const int j = tid % 42, r = tid / 42;   // 12 reducers per moment
        double s = 0.0;
        for (int i = r; i < BB * SS; i += 12) s += (double)part1[(size_t)i * 42 + j];
        red[tid] = s;
    }
    __syncthreads();
    if (tid < 42) {
        double s = 0.0;
        for (int r = 0; r < 12; ++r) s += red[r * 42 + tid];
        tot[tid] = s / (double)MTOT;
    }
    __syncthreads();
    if (tid < 64) {
        double m1 = 0.0;
        for (int c = 0; c < 6; ++c) m1 += (double)w0[tid * 6 + c] * tot[c];
        double e2 = 0.0;
        for (int c = 0; c < 6; ++c)
            for (int d = 0; d < 6; ++d)
                e2 += (double)w0[tid * 6 + c] * (double)w0[tid * 6 + d] * tot[6 + c * 6 + d];
        double var = e2 - m1 * m1;
        if (var < 0.0) var = 0.0;
        const double A = (double)g0[tid] / sqrt(var + 1e-5);
        Asf[tid] = (float)A;
        c1[tid] = (float)((double)bt0[tid] - A * m1);
    }
    __syncthreads();
    if (tid < 256) {
        const int l = tid & 63;
        const int o = (tid >> 6) * 16 + (l & 15);
        const int h = l >> 4;
#pragma unroll
        for (int j = 0; j < 8; ++j) {
            const float val = (h == 0 && j < 6) ? Asf[o] * w0[o * 6 + j] : 0.f;
            wf1[tid * 8 + j] = (short)f2bf(val);
        }
    }
}

// ---------------------------------------------------------------------------
// MFMA chain kernel. 256 thr = 4 waves; wave processes 32 points (one group)
// per tile-iter as 2 m-steps of 16. Per m-step: L1 (4 mfma, K padded),
// LDS H round-trip [m][k] bf16 (36-dword rows), L2 (8 mfma), and for PHASE 3
// folded-L2 -> H2 -> L3 (16 mfma, W3 frags staged in LDS).
// Stats accumulate in static regs; group-max via wave-private LDS transpose.
// PHASE 2: stats of x2_nb. PHASE 3: stats of x3_nb + gmax (pre-BN3; BN3+relu
// +max commute since A3>0 -> final_out applies it).
// ---------------------------------------------------------------------------
template<int PHASE>
__global__ __launch_bounds__(256, 2) void chain_kernel(
    const float* __restrict__ v,
    const short* __restrict__ wf1, const float* __restrict__ c1,
    const short* __restrict__ wf2, const float* __restrict__ c2,
    const short* __restrict__ wf3,
    float* __restrict__ part, float* __restrict__ gmax, int tpb)
{
    __shared__ alignas(16) unsigned Hu1[4][16][36];
    __shared__ alignas(16) unsigned Hu2[(PHASE == 3) ? 4 : 1][16][36];
    __shared__ alignas(16) short w3l[(PHASE == 3) ? 8192 : 8];
    __shared__ alignas(16) float gm[(PHASE == 3) ? 4 : 1][128][20];
    __shared__ float redf[4][4][64];

    const int tid = threadIdx.x;
    const int w = tid >> 6, l = tid & 63;
    const int mcol = l & 15, h = l >> 4;

    if constexpr (PHASE == 3) {
        const unsigned* src = (const unsigned*)wf3;
        unsigned* dst = (unsigned*)w3l;
        for (int i = tid; i < 4096; i += 256) dst[i] = src[i];
    }
    __syncthreads();

    // persistent weight frags + BN constants
    bfrag a1[4];
#pragma unroll
    for (int t = 0; t < 4; ++t) a1[t] = *(const bfrag*)&wf1[(t * 64 + l) * 8];
    bfrag a2[8];
#pragma unroll
    for (int f = 0; f < 8; ++f) a2[f] = *(const bfrag*)&wf2[(f * 64 + l) * 8];
    float c1v[16];
#pragma unroll
    for (int t = 0; t < 4; ++t)
#pragma unroll
        for (int r = 0; r < 4; ++r) c1v[t * 4 + r] = c1[t * 16 + h * 4 + r];
    float c2v[16];
    if constexpr (PHASE == 3) {
#pragma unroll
        for (int t = 0; t < 4; ++t)
#pragma unroll
            for (int r = 0; r < 4; ++r) c2v[t * 4 + r] = c2[t * 16 + h * 4 + r];
    }

    constexpr int NS = (PHASE == 3) ? 32 : 16;
    float sA[NS], qA[NS];
#pragma unroll
    for (int i = 0; i < NS; ++i) { sA[i] = 0.f; qA[i] = 0.f; }

    const facc zf = {0.f, 0.f, 0.f, 0.f};

    for (int ti = 0; ti < tpb; ++ti) {
        const int tile = blockIdx.x * tpb + ti;
        float mx[(PHASE == 3) ? 32 : 1];
        if constexpr (PHASE == 3) {
#pragma unroll
            for (int i = 0; i < 32; ++i) mx[i] = -3.0e38f;
        }

#pragma unroll
        for (int st = 0; st < 2; ++st) {
            const int mg = tile * 128 + w * 32 + st * 16 + mcol;

            // ---- L1: x1 = fold(W1) * v ----
            bfrag bv;
#pragma unroll
            for (int j = 0; j < 8; ++j) bv[j] = 0;
            if (h == 0) {
#pragma unroll
                for (int j = 0; j < 6; ++j)
                    bv[j] = (short)f2bf(v[(size_t)j * MTOT + mg]);
            }
            facc x1[4];
#pragma unroll
            for (int t = 0; t < 4; ++t) x1[t] = MFMA16(a1[t], bv, zf);
            // h1 = relu(x1 + c1), pack bf16 pairs -> Hu1[m][k]
#pragma unroll
            for (int t = 0; t < 4; ++t)
#pragma unroll
                for (int rr = 0; rr < 2; ++rr)
                    Hu1[w][mcol][t * 8 + h * 2 + rr] = packbf(
                        fmaxf(x1[t][2 * rr]     + c1v[t * 4 + 2 * rr],     0.f),
                        fmaxf(x1[t][2 * rr + 1] + c1v[t * 4 + 2 * rr + 1], 0.f));

            // ---- L2 b-frags ----
            const bfrag b0 = *(const bfrag*)&Hu1[w][mcol][h * 4];
            const bfrag b1 = *(const bfrag*)&Hu1[w][mcol][16 + h * 4];

            if constexpr (PHASE == 2) {
#pragma unroll
                for (int t = 0; t < 4; ++t) {
                    facc a = MFMA16(a2[2 * t], b0, zf);
                    a = MFMA16(a2[2 * t + 1], b1, a);
#pragma unroll
                    for (int r = 0; r < 4; ++r) {
                        const float x = a[r];
                        sA[t * 4 + r] += x;
                        qA[t * 4 + r] = fmaf(x, x, qA[t * 4 + r]);
                    }
                }
            } else {
                // folded L2 -> h2 -> Hu2
#pragma unroll
                for (int t = 0; t < 4; ++t) {
                    facc a = MFMA16(a2[2 * t], b0, zf);
                    a = MFMA16(a2[2 * t + 1], b1, a);
#pragma unroll
                    for (int rr = 0; rr < 2; ++rr)
                        Hu2[w][mcol][t * 8 + h * 2 + rr] = packbf(
                            fmaxf(a[2 * rr]     + c2v[t * 4 + 2 * rr],     0.f),
                            fmaxf(a[2 * rr + 1] + c2v[t * 4 + 2 * rr + 1], 0.f));
                }
                const bfrag d0 = *(const bfrag*)&Hu2[w][mcol][h * 4];
                const bfrag d1 = *(const bfrag*)&Hu2[w][mcol][16 + h * 4];
                // ---- L3: 8 o-tiles x 2 k-chunks ----
#pragma unroll
                for (int t3 = 0; t3 < 8; ++t3) {
                    const bfrag wa = *(const bfrag*)&w3l[((t3 * 2 + 0) * 64 + l) * 8];
                    const bfrag wb = *(const bfrag*)&w3l[((t3 * 2 + 1) * 64 + l) * 8];
                    facc a = MFMA16(wa, d0, zf);
                    a = MFMA16(wb, d1, a);
#pragma unroll
                    for (int r = 0; r < 4; ++r) {
                        const float x = a[r];
                        const int i = t3 * 4 + r;
                        sA[i] += x;
                        qA[i] = fmaf(x, x, qA[i]);
                        mx[i] = fmaxf(mx[i], x);
                    }
                }
            }
        }

        if constexpr (PHASE == 3) {
            // group-max across the 16 lane-columns via LDS transpose
#pragma unroll
            for (int t3 = 0; t3 < 8; ++t3)
#pragma unroll
                for (int r = 0; r < 4; ++r)
                    gm[w][t3 * 16 + h * 4 + r][mcol] = mx[t3 * 4 + r];
            // wave-private; compiler inserts lgkmcnt
            float m0 = -3.0e38f, m1 = -3.0e38f;
#pragma unroll
            for (int c4i = 0; c4i < 4; ++c4i) {
                const facc v0 = *(const facc*)&gm[w][2 * l][c4i * 4];
                const facc v1 = *(const facc*)&gm[w][2 * l + 1][c4i * 4];
#pragma unroll
                for (int jj = 0; jj < 4; ++jj) {
                    m0 = fmaxf(m0, v0[jj]);
                    m1 = fmaxf(m1, v1[jj]);
                }
            }
            const int g = tile * 4 + w;
            gmax[(size_t)g * 128 + 2 * l]     = m0;
            gmax[(size_t)g * 128 + 2 * l + 1] = m1;
        }
    }

    // ---- stats reduce: in-wave over the 16 lane-columns, then cross-wave ----
#pragma unroll
    for (int off = 1; off < 16; off <<= 1) {
#pragma unroll
        for (int i = 0; i < NS; ++i) {
            sA[i] += __shfl_xor(sA[i], off);
            qA[i] += __shfl_xor(qA[i], off);
        }
    }
    __syncthreads();   // all waves done with gm (redf is separate, but keep ordering clean)
    if (mcol == 0) {
#pragma unroll
        for (int i = 0; i < NS; ++i) {
            redf[w][h][i] = sA[i];
            redf[w][h][NS + i] = qA[i];
        }
    }
    __syncthreads();
    if constexpr (PHASE == 2) {
        if (tid < 128) {
            const int o = tid & 63, sq = tid >> 6;
            const int i = (o >> 4) * 4 + (o & 3), hh = (o >> 2) & 3;
            const int idx = sq * 16 + i;
            const float s = redf[0][hh][idx] + redf[1][hh][idx] +
                            redf[2][hh][idx] + redf[3][hh][idx];
            part[(size_t)blockIdx.x * 128 + sq * 64 + o] = s;
        }
    } else {
        if (tid < 256) {
            const int o = tid & 127, sq = tid >> 7;
            const int i = (o >> 4) * 4 + (o & 3), hh = (o >> 2) & 3;
            const int idx = sq * 32 + i;
            const float s = redf[0][hh][idx] + redf[1][hh][idx] +
                            redf[2][hh][idx] + redf[3][hh][idx];
            part[(size_t)blockIdx.x * 256 + sq * 128 + o] = s;
        }
    }
}

// ---------------------------------------------------------------------------
// finalize2: reduce chain<2> partials (2048 x [s64|q64]) -> A2/c2; emit
// folded bf16 W2 A-frags.
// ---------------------------------------------------------------------------
__global__ __launch_bounds__(512) void finalize2_kernel(const float* __restrict__ part,
                                                        const float* __restrict__ w1g,
                                                        const float* __restrict__ g1,
                                                        const float* __restrict__ bt1,
                                                        short* __restrict__ wf2f,
                                                        float* __restrict__ c2)
{
    __shared__ double tot[512];
    __shared__ float As[64];
    const int tid = threadIdx.x;
    const int j = tid & 127, r = tid >> 7;    // 4 reducers per stat
    double s = 0.0;
    for (int blk = r; blk < 2048; blk += 4) s += (double)part[(size_t)blk * 128 + j];
    tot[tid] = s;
    __syncthreads();
    if (tid < 128) tot[tid] = tot[tid] + tot[128 + tid] + tot[256 + tid] + tot[384 + tid];
    __syncthreads();
    if (tid < 64) {
        const double mean = tot[tid] / (double)MTOT;
        double var = tot[64 + tid] / (double)MTOT - mean * mean;
        if (var < 0.0) var = 0.0;
        const double A = (double)g1[tid] / sqrt(var + 1e-5);
        As[tid] = (float)A;
        c2[tid] = (float)((double)bt1[tid] - A * mean);
    }
    __syncthreads();
    {
        const int f = tid >> 6, l = tid & 63;
        const int o = (f >> 1) * 16 + (l & 15);
        const int kb = (f & 1) * 32 + (l >> 4) * 8;
#pragma unroll
        for (int j8 = 0; j8 < 8; ++j8)
            wf2f[tid * 8 + j8] = (short)f2bf(As[o] * w1g[o * 64 + kb + j8]);
    }
}

// ---------------------------------------------------------------------------
// finalize3: reduce chain<3> partials (2048 x [s128|q128]) -> A3/c3.
// ---------------------------------------------------------------------------
__global__ __launch_bounds__(512) void finalize3_kernel(const float* __restrict__ part,
                                                        const float* __restrict__ g2,
                                                        const float* __restrict__ bt2,
                                                        float* __restrict__ A3,
                                                        float* __restrict__ c3)
{
    __shared__ double tot[512];
    const int tid = threadIdx.x;
    const int j = tid & 255, r = tid >> 8;    // 2 reducers per stat
    double s = 0.0;
    for (int blk = r; blk < 2048; blk += 2) s += (double)part[(size_t)blk * 256 + j];
    tot[tid] = s;
    __syncthreads();
    if (tid < 256) tot[tid] = tot[tid] + tot[256 + tid];
    __syncthreads();
    if (tid < 128) {
        const double mean = tot[tid] / (double)MTOT;
        double var = tot[128 + tid] / (double)MTOT - mean * mean;
        if (var < 0.0) var = 0.0;
        const double A = (double)g2[tid] / sqrt(var + 1e-5);
        A3[tid] = (float)A;
        c3[tid] = (float)((double)bt2[tid] - A * mean);
    }
}

// ---------------------------------------------------------------------------
// final_out: in-place out = relu(A3*gmax + c3) over (16384 groups x 128 ch).
// ---------------------------------------------------------------------------
__global__ __launch_bounds__(256) void final_out_kernel(float* __restrict__ outF,
                                                        const float* __restrict__ A3,
                                                        const float* __restrict__ c3)
{
    __shared__ float As[128], Cs[128];
    const int tid = threadIdx.x;
    if (tid < 128) { As[tid] = A3[tid]; Cs[tid] = c3[tid]; }
    __syncthreads();
    const int idx = (int)blockIdx.x * 256 + tid;      // f4 index, total 524288
    f4 val = *reinterpret_cast<f4*>(&outF[(size_t)idx * 4]);
    const int chb = (idx * 4) & 127;
#pragma unroll
    for (int jj = 0; jj < 4; ++jj)
        val.v[jj] = fmaxf(fmaf(As[chb + jj], val.v[jj], Cs[chb + jj]), 0.f);
    *reinterpret_cast<f4*>(&outF[(size_t)idx * 4]) = val;
}

// ---------------------------------------------------------------------------
extern "C" void kernel_launch(void* const* d_in, const int* in_sizes, int n_in,
                              void* d_out, int out_size, void* d_ws, size_t ws_size,
                              hipStream_t stream)
{
    const float* xyz  = (const float*)d_in[0];
    const float* feat = (const float*)d_in[1];
    const float* w0  = (const float*)d_in[2];
    const float* g0  = (const float*)d_in[4];
    const float* bt0 = (const float*)d_in[5];
    const float* w1  = (const float*)d_in[6];
    const float* g1  = (const float*)d_in[8];
    const float* bt1 = (const float*)d_in[9];
    const float* w2  = (const float*)d_in[10];
    const float* g2  = (const float*)d_in[12];
    const float* bt2 = (const float*)d_in[13];

    float* out    = (float*)d_out;
    float* newxyz = out;                 // (16,1024,3)
    float* outF   = out + BB * SS * 3;   // (16,1024,128) — gmax then final

    float* wsf  = (float*)d_ws;
    float* v    = wsf;                         // 3145728 floats
    float* part = wsf + 6ull * MTOT;           // 688128 (moments / stat partials)
    float* c1   = part + 688128;               // 64
    float* c2   = c1 + 64;                     // 64
    float* A3   = c2 + 64;                     // 128
    float* c3   = A3 + 128;                    // 128
    short* wf1  = (short*)(c3 + 128);          // 2048 shorts (4 frags)
    short* wf2r = wf1 + 2048;                  // 4096 shorts (8 frags, raw)
    short* wf2f = wf2r + 4096;                 // 4096 shorts (8 frags, folded)
    short* wf3  = wf2f + 4096;                 // 8192 shorts (16 frags, raw)

    prep_kernel<<<dim3(1), dim3(512), 0, stream>>>(w1, w2, wf2r, wf3);
    fps_kernel<<<dim3(BB), dim3(256), 0, stream>>>(xyz, newxyz);
    ball_gather_kernel<<<dim3(4096), dim3(256), 0, stream>>>(xyz, feat, newxyz, v, part);
    finalize1_kernel<<<dim3(1), dim3(512), 0, stream>>>(part, w0, g0, bt0, wf1, c1);

    chain_kernel<2><<<dim3(2048), dim3(256), 0, stream>>>(v, wf1, c1, wf2r, nullptr,
                                                          nullptr, part, nullptr, 2);
    finalize2_kernel<<<dim3(1), dim3(512), 0, stream>>>(part, w1, g1, bt1, wf2f, c2);

    chain_kernel<3><<<dim3(2048), dim3(256), 0, stream>>>(v, wf1, c1, wf2f, c2,
                                                          wf3, part, outF, 2);
    finalize3_kernel<<<dim3(1), dim3(512), 0, stream>>>(part, g2, bt2, A3, c3);
    final_out_kernel<<<dim3(2048), dim3(256), 0, stream>>>(outF, A3, c3);
}

// Round 8
// 1902.457 us; speedup vs baseline: 2.4994x; 1.0560x over previous
//
#include <hip/hip_runtime.h>
#include <math.h>

// Problem constants
#define BB 16
#define NN 8192
#define SS 1024
#define GG 32
#define MTOT (BB*SS*GG)   // 524288
// MLP: 6 -> 64 -> 64 -> 128

struct alignas(16) f4 { float v[4]; };

typedef __attribute__((ext_vector_type(8))) short bfrag;   // 8 bf16 = 4 VGPR
typedef __attribute__((ext_vector_type(4))) float facc;    // 4 f32 acc

#define MFMA16(a, b, c) __builtin_amdgcn_mfma_f32_16x16x32_bf16(a, b, c, 0, 0, 0)

__device__ __forceinline__ unsigned short f2bf(float f) {
    const unsigned u = __float_as_uint(f);
    return (unsigned short)((u + 0x7FFFu + ((u >> 16) & 1u)) >> 16);
}
__device__ __forceinline__ unsigned packbf(float lo, float hi) {
    return (unsigned)f2bf(lo) | ((unsigned)f2bf(hi) << 16);
}

template<int CTRL>
__device__ __forceinline__ int dppmov(int x) {
    return __builtin_amdgcn_update_dpp(x, x, CTRL, 0xF, 0xF, true);
}
// one u64 max-reduce level via DPP permutation of (hi,lo)
template<int CTRL>
__device__ __forceinline__ void dlevel(int& hi, int& lo) {
    const int oh = dppmov<CTRL>(hi);
    const int ol = dppmov<CTRL>(lo);
    const unsigned long long o =
        ((unsigned long long)(unsigned)oh << 32) | (unsigned)ol;
    const unsigned long long c =
        ((unsigned long long)(unsigned)hi << 32) | (unsigned)lo;
    if (o > c) { hi = oh; lo = ol; }
}

// ---------------------------------------------------------------------------
// prep: build RAW bf16 A-frags for W2 (8 frags) and W3 (16 frags).
// Frag layout: entry (f, lane l): A[o][k], o = (f>>1)*16 + (l&15),
// k = (f&1)*32 + (l>>4)*8 + j, j=0..7. Stored flat: [(f*64+l)*8 + j].
// ---------------------------------------------------------------------------
__global__ __launch_bounds__(512) void prep_kernel(const float* __restrict__ w1g,
                                                   const float* __restrict__ w2g,
                                                   short* __restrict__ wf2r,
                                                   short* __restrict__ wf3r)
{
    const int tid = threadIdx.x;
    {
        const int f = tid >> 6, l = tid & 63;
        const int o = (f >> 1) * 16 + (l & 15);
        const int kb = (f & 1) * 32 + (l >> 4) * 8;
#pragma unroll
        for (int j = 0; j < 8; ++j)
            wf2r[tid * 8 + j] = (short)f2bf(w1g[o * 64 + kb + j]);
    }
    for (int idx = tid; idx < 1024; idx += 512) {
        const int f = idx >> 6, l = idx & 63;
        const int o = (f >> 1) * 16 + (l & 15);
        const int kb = (f & 1) * 32 + (l >> 4) * 8;
#pragma unroll
        for (int j = 0; j < 8; ++j)
            wf3r[idx * 8 + j] = (short)f2bf(w2g[o * 64 + kb + j]);
    }
}

// ---------------------------------------------------------------------------
// FPS. One block/batch, 256 thr, 32 pts/thread in regs, coords in LDS, one
// barrier per step. Distance math: EXACT __fsub_rn/__fmul_rn/__fadd_rn only
// (never pragma-based — contraction immunity must be intrinsic; round-7
// lesson). In-thread argmax: strict float > (ascending k keeps lowest index,
// equivalent to u64 key max). Wave reduce: u64 (dist,inv-idx) max via DPP
// ROW_ROR 1/2/4/8 (covers each 16-row) + shfl xor16/xor32.
// ---------------------------------------------------------------------------
__global__ __launch_bounds__(256) void fps_kernel(const float* __restrict__ xyz,
                                                  float* __restrict__ newxyz)
{
    __shared__ float lx[NN], ly[NN], lz[NN];            // 96 KB
    __shared__ unsigned long long slots[2][4];
    const int b = blockIdx.x;
    const int t = threadIdx.x;
    const int wave = t >> 6, lane = t & 63;
    const float* base = xyz + (size_t)b * NN * 3;

    float px[32], py[32], pz[32], dd[32];
#pragma unroll
    for (int k = 0; k < 32; ++k) {
        const int p = (k << 8) + t;
        const float x = base[p * 3 + 0];
        const float y = base[p * 3 + 1];
        const float z = base[p * 3 + 2];
        px[k] = x; py[k] = y; pz[k] = z; dd[k] = 1e10f;
        lx[p] = x; ly[p] = y; lz[p] = z;
    }
    __syncthreads();

    int far = 0;
    float* outb = newxyz + (size_t)b * SS * 3;
    for (int s = 0; s < SS; ++s) {
        const float cx = lx[far], cy = ly[far], cz = lz[far];
        if (t == 0) {
            outb[s * 3 + 0] = cx;
            outb[s * 3 + 1] = cy;
            outb[s * 3 + 2] = cz;
        }
        float bf = -1.f;
        unsigned binv = 0u;
#pragma unroll
        for (int k = 0; k < 32; ++k) {
            const float dx = __fsub_rn(px[k], cx);
            const float dy = __fsub_rn(py[k], cy);
            const float dz = __fsub_rn(pz[k], cz);
            const float d  = __fadd_rn(__fadd_rn(__fmul_rn(dx, dx), __fmul_rn(dy, dy)),
                                       __fmul_rn(dz, dz));
            const float nd = fminf(dd[k], d);
            dd[k] = nd;
            if (nd > bf) {                         // strict > keeps lowest k
                bf = nd;
                binv = 0xFFFFFFFFu - (unsigned)((k << 8) + t);
            }
        }

        int hi = __float_as_int(bf);   // bf >= 0 -> monotone bit pattern
        int lo = (int)binv;
        dlevel<0x121>(hi, lo);         // ROW_ROR:1
        dlevel<0x122>(hi, lo);         // ROW_ROR:2
        dlevel<0x124>(hi, lo);         // ROW_ROR:4
        dlevel<0x128>(hi, lo);         // ROW_ROR:8  -> max over each 16-row
        {
            const int oh = __shfl_xor(hi, 16), ol = __shfl_xor(lo, 16);
            const unsigned long long o =
                ((unsigned long long)(unsigned)oh << 32) | (unsigned)ol;
            const unsigned long long c =
                ((unsigned long long)(unsigned)hi << 32) | (unsigned)lo;
            if (o > c) { hi = oh; lo = ol; }
        }
        {
            const int oh = __shfl_xor(hi, 32), ol = __shfl_xor(lo, 32);
            const unsigned long long o =
                ((unsigned long long)(unsigned)oh << 32) | (unsigned)ol;
            const unsigned long long c =
                ((unsigned long long)(unsigned)hi << 32) | (unsigned)lo;
            if (o > c) { hi = oh; lo = ol; }
        }

        if (lane == 0)
            slots[s & 1][wave] =
                ((unsigned long long)(unsigned)hi << 32) | (unsigned)lo;
        __syncthreads();
        unsigned long long g = slots[s & 1][0];
#pragma unroll
        for (int w = 1; w < 4; ++w) {
            const unsigned long long o = slots[s & 1][w];
            g = (o > g) ? o : g;
        }
        far = (int)(0xFFFFFFFFu - (unsigned)(g & 0xFFFFFFFFull));
    }
}

// ---------------------------------------------------------------------------
// ball query + gather + v first/second moments (analytic BN1 stats).
// ---------------------------------------------------------------------------
__global__ __launch_bounds__(256) void ball_gather_kernel(const float* __restrict__ xyz,
                                                          const float* __restrict__ feat,
                                                          const float* __restrict__ newxyz,
                                                          float* __restrict__ v,
                                                          float* __restrict__ part1)
{
    const int wid  = (int)((blockIdx.x * 256 + threadIdx.x) >> 6);
    const int lane = threadIdx.x & 63;
    if (wid >= BB * SS) return;
    const int b = wid >> 10;

    const float cx = newxyz[wid * 3 + 0];
    const float cy = newxyz[wid * 3 + 1];
    const float cz = newxyz[wid * 3 + 2];
    const float* xb = xyz + (size_t)b * NN * 3;
    const float* fb = feat + (size_t)b * NN * 3;
    const size_t mbase = (size_t)wid * GG;

    float mS[6];
    float mP[36];
#pragma unroll
    for (int c = 0; c < 6; ++c) mS[c] = 0.f;
#pragma unroll
    for (int c = 0; c < 36; ++c) mP[c] = 0.f;

    int cnt = 0, firstp = -1;
    for (int base = 0; base < NN && cnt < GG; base += 64) {
        const int p = base + lane;
        const float x = xb[p * 3 + 0], y = xb[p * 3 + 1], z = xb[p * 3 + 2];
        const float dx = __fsub_rn(cx, x);
        const float dy = __fsub_rn(cy, y);
        const float dz = __fsub_rn(cz, z);
        const float d  = __fadd_rn(__fadd_rn(__fmul_rn(dx, dx), __fmul_rn(dy, dy)),
                                   __fmul_rn(dz, dz));
        const bool hit = (d <= 0.04f);
        const unsigned long long m = __ballot(hit);
        if (firstp < 0 && m != 0ull) firstp = base + (int)__builtin_ctzll(m);
        const int pos = cnt + (int)__popcll(m & ((1ull << lane) - 1ull));
        if (hit && pos < GG) {
            const size_t mm = mbase + pos;
            float a[6];
            a[0] = __fsub_rn(x, cx);
            a[1] = __fsub_rn(y, cy);
            a[2] = __fsub_rn(z, cz);
            a[3] = fb[p * 3 + 0];
            a[4] = fb[p * 3 + 1];
            a[5] = fb[p * 3 + 2];
#pragma unroll
            for (int c = 0; c < 6; ++c) {
                v[(size_t)c * MTOT + mm] = a[c];
                mS[c] += a[c];
#pragma unroll
                for (int dch = 0; dch < 6; ++dch)
                    mP[c * 6 + dch] = fmaf(a[c], a[dch], mP[c * 6 + dch]);
            }
        }
        cnt += (int)__popcll(m);
    }
    if (cnt < GG) {
        const int p = firstp;
        const float x = xb[p * 3 + 0], y = xb[p * 3 + 1], z = xb[p * 3 + 2];
        float a[6];
        a[0] = __fsub_rn(x, cx);
        a[1] = __fsub_rn(y, cy);
        a[2] = __fsub_rn(z, cz);
        a[3] = fb[p * 3 + 0];
        a[4] = fb[p * 3 + 1];
        a[5] = fb[p * 3 + 2];
        for (int j = cnt + lane; j < GG; j += 64) {
            const size_t mm = mbase + j;
#pragma unroll
            for (int c = 0; c < 6; ++c) {
                v[(size_t)c * MTOT + mm] = a[c];
                mS[c] += a[c];
#pragma unroll
                for (int dch = 0; dch < 6; ++dch)
                    mP[c * 6 + dch] = fmaf(a[c], a[dch], mP[c * 6 + dch]);
            }
        }
    }
#pragma unroll
    for (int off = 1; off < 64; off <<= 1) {
#pragma unroll
        for (int c = 0; c < 6; ++c) mS[c] += __shfl_xor(mS[c], off);
#pragma unroll
        for (int c = 0; c < 36; ++c) mP[c] += __shfl_xor(mP[c], off);
    }
    if (lane == 0) {
        float* row = part1 + (size_t)wid * 42;
#pragma unroll
        for (int c = 0; c < 6; ++c) row[c] = mS[c];
#pragma unroll
        for (int c = 0; c < 36; ++c) row[6 + c] = mP[c];
    }
}

// ---------------------------------------------------------------------------
// finalize1: analytic BN1 from v moments; emit folded bf16 W1 A-frags
// (4 frags; only lanes h==0, j<6 nonzero) and c1[64] (f32).
// ---------------------------------------------------------------------------
__global__ __launch_bounds__(512) void finalize1_kernel(const float* __restrict__ part1,
                                                        const float* __restrict__ w0,
                                                        const float* __restrict__ g0,
                                                        const float* __restrict__ bt0,
                                                        short* __restrict__ wf1,
                                                        float* __restrict__ c1)
{
    __shared__ double red[504];
    __shared__ double tot[42];
    __shared__ float Asf[64];
    const int tid = threadIdx.x;
    if (tid < 504) {
        const int j = tid % 42, r = tid / 42;   // 12 reducers per moment
        double s = 0.0;
        for (int i = r; i < BB * SS; i += 12) s += (double)part1[(size_t)i * 42 + j];
        red[tid] = s;
    }
    __syncthreads();
    if (tid < 42) {
        double s = 0.0;
        for (int r = 0; r < 12; ++r) s += red[r * 42 + tid];
        tot[tid] = s / (double)MTOT;
    }
    __syncthreads();
    if (tid < 64) {
        double m1 = 0.0;
        for (int c = 0; c < 6; ++c) m1 += (double)w0[tid * 6 + c] * tot[c];
        double e2 = 0.0;
        for (int c = 0; c < 6; ++c)
            for (int d = 0; d < 6; ++d)
                e2 += (double)w0[tid * 6 + c] * (double)w0[tid * 6 + d] * tot[6 + c * 6 + d];
        double var = e2 - m1 * m1;
        if (var < 0.0) var = 0.0;
        const double A = (double)g0[tid] / sqrt(var + 1e-5);
        Asf[tid] = (float)A;
        c1[tid] = (float)((double)bt0[tid] - A * m1);
    }
    __syncthreads();
    if (tid < 256) {
        const int l = tid & 63;
        const int o = (tid >> 6) * 16 + (l & 15);
        const int h = l >> 4;
#pragma unroll
        for (int j = 0; j < 8; ++j) {
            const float val = (h == 0 && j < 6) ? Asf[o] * w0[o * 6 + j] : 0.f;
            wf1[tid * 8 + j] = (short)f2bf(val);
        }
    }
}

// ---------------------------------------------------------------------------
// MFMA chain kernel (round-6 design, unchanged). 256 thr = 4 waves; wave
// processes one 32-pt group per tile-iter as 2 m-steps of 16.
// PHASE 2: stats of x2_nb. PHASE 3: stats of x3_nb + pre-BN3 group max.
// ---------------------------------------------------------------------------
template<int PHASE>
__global__ __launch_bounds__(256, 2) void chain_kernel(
    const float* __restrict__ v,
    const short* __restrict__ wf1, const float* __restrict__ c1,
    const short* __restrict__ wf2, const float* __restrict__ c2,
    const short* __restrict__ wf3,
    float* __restrict__ part, float* __restrict__ gmax, int tpb)
{
    __shared__ alignas(16) unsigned Hu1[4][16][36];
    __shared__ alignas(16) unsigned Hu2[(PHASE == 3) ? 4 : 1][16][36];
    __shared__ alignas(16) short w3l[(PHASE == 3) ? 8192 : 8];
    __shared__ alignas(16) float gm[(PHASE == 3) ? 4 : 1][128][20];
    __shared__ float redf[4][4][64];

    const int tid = threadIdx.x;
    const int w = tid >> 6, l = tid & 63;
    const int mcol = l & 15, h = l >> 4;

    if constexpr (PHASE == 3) {
        const unsigned* src = (const unsigned*)wf3;
        unsigned* dst = (unsigned*)w3l;
        for (int i = tid; i < 4096; i += 256) dst[i] = src[i];
    }
    __syncthreads();

    bfrag a1[4];
#pragma unroll
    for (int t = 0; t < 4; ++t) a1[t] = *(const bfrag*)&wf1[(t * 64 + l) * 8];
    bfrag a2[8];
#pragma unroll
    for (int f = 0; f < 8; ++f) a2[f] = *(const bfrag*)&wf2[(f * 64 + l) * 8];
    float c1v[16];
#pragma unroll
    for (int t = 0; t < 4; ++t)
#pragma unroll
        for (int r = 0; r < 4; ++r) c1v[t * 4 + r] = c1[t * 16 + h * 4 + r];
    float c2v[16];
    if constexpr (PHASE == 3) {
#pragma unroll
        for (int t = 0; t < 4; ++t)
#pragma unroll
            for (int r = 0; r < 4; ++r) c2v[t * 4 + r] = c2[t * 16 + h * 4 + r];
    }

    constexpr int NS = (PHASE == 3) ? 32 : 16;
    float sA[NS], qA[NS];
#pragma unroll
    for (int i = 0; i < NS; ++i) { sA[i] = 0.f; qA[i] = 0.f; }

    const facc zf = {0.f, 0.f, 0.f, 0.f};

    for (int ti = 0; ti < tpb; ++ti) {
        const int tile = blockIdx.x * tpb + ti;
        float mx[(PHASE == 3) ? 32 : 1];
        if constexpr (PHASE == 3) {
#pragma unroll
            for (int i = 0; i < 32; ++i) mx[i] = -3.0e38f;
        }

#pragma unroll
        for (int st = 0; st < 2; ++st) {
            const int mg = tile * 128 + w * 32 + st * 16 + mcol;

            bfrag bv;
#pragma unroll
            for (int j = 0; j < 8; ++j) bv[j] = 0;
            if (h == 0) {
#pragma unroll
                for (int j = 0; j < 6; ++j)
                    bv[j] = (short)f2bf(v[(size_t)j * MTOT + mg]);
            }
            facc x1[4];
#pragma unroll
            for (int t = 0; t < 4; ++t) x1[t] = MFMA16(a1[t], bv, zf);
#pragma unroll
            for (int t = 0; t < 4; ++t)
#pragma unroll
                for (int rr = 0; rr < 2; ++rr)
                    Hu1[w][mcol][t * 8 + h * 2 + rr] = packbf(
                        fmaxf(x1[t][2 * rr]     + c1v[t * 4 + 2 * rr],     0.f),
                        fmaxf(x1[t][2 * rr + 1] + c1v[t * 4 + 2 * rr + 1], 0.f));

            const bfrag b0 = *(const bfrag*)&Hu1[w][mcol][h * 4];
            const bfrag b1 = *(const bfrag*)&Hu1[w][mcol][16 + h * 4];

            if constexpr (PHASE == 2) {
#pragma unroll
                for (int t = 0; t < 4; ++t) {
                    facc a = MFMA16(a2[2 * t], b0, zf);
                    a = MFMA16(a2[2 * t + 1], b1, a);
#pragma unroll
                    for (int r = 0; r < 4; ++r) {
                        const float x = a[r];
                        sA[t * 4 + r] += x;
                        qA[t * 4 + r] = fmaf(x, x, qA[t * 4 + r]);
                    }
                }
            } else {
#pragma unroll
                for (int t = 0; t < 4; ++t) {
                    facc a = MFMA16(a2[2 * t], b0, zf);
                    a = MFMA16(a2[2 * t + 1], b1, a);
#pragma unroll
                    for (int rr = 0; rr < 2; ++rr)
                        Hu2[w][mcol][t * 8 + h * 2 + rr] = packbf(
                            fmaxf(a[2 * rr]     + c2v[t * 4 + 2 * rr],     0.f),
                            fmaxf(a[2 * rr + 1] + c2v[t * 4 + 2 * rr + 1], 0.f));
                }
                const bfrag d0 = *(const bfrag*)&Hu2[w][mcol][h * 4];
                const bfrag d1 = *(const bfrag*)&Hu2[w][mcol][16 + h * 4];
#pragma unroll
                for (int t3 = 0; t3 < 8; ++t3) {
                    const bfrag wa = *(const bfrag*)&w3l[((t3 * 2 + 0) * 64 + l) * 8];
                    const bfrag wb = *(const bfrag*)&w3l[((t3 * 2 + 1) * 64 + l) * 8];
                    facc a = MFMA16(wa, d0, zf);
                    a = MFMA16(wb, d1, a);
#pragma unroll
                    for (int r = 0; r < 4; ++r) {
                        const float x = a[r];
                        const int i = t3 * 4 + r;
                        sA[i] += x;
                        qA[i] = fmaf(x, x, qA[i]);
                        mx[i] = fmaxf(mx[i], x);
                    }
                }
            }
        }

        if constexpr (PHASE == 3) {
#pragma unroll
            for (int t3 = 0; t3 < 8; ++t3)
#pragma unroll
                for (int r = 0; r < 4; ++r)
                    gm[w][t3 * 16 + h * 4 + r][mcol] = mx[t3 * 4 + r];
            float m0 = -3.0e38f, m1 = -3.0e38f;
#pragma unroll
            for (int c4i = 0; c4i < 4; ++c4i) {
                const facc v0 = *(const facc*)&gm[w][2 * l][c4i * 4];
                const facc v1 = *(const facc*)&gm[w][2 * l + 1][c4i * 4];
#pragma unroll
                for (int jj = 0; jj < 4; ++jj) {
                    m0 = fmaxf(m0, v0[jj]);
                    m1 = fmaxf(m1, v1[jj]);
                }
            }
            const int g = tile * 4 + w;
            gmax[(size_t)g * 128 + 2 * l]     = m0;
            gmax[(size_t)g * 128 + 2 * l + 1] = m1;
        }
    }

#pragma unroll
    for (int off = 1; off < 16; off <<= 1) {
#pragma unroll
        for (int i = 0; i < NS; ++i) {
            sA[i] += __shfl_xor(sA[i], off);
            qA[i] += __shfl_xor(qA[i], off);
        }
    }
    __syncthreads();
    if (mcol == 0) {
#pragma unroll
        for (int i = 0; i < NS; ++i) {
            redf[w][h][i] = sA[i];
            redf[w][h][NS + i] = qA[i];
        }
    }
    __syncthreads();
    if constexpr (PHASE == 2) {
        if (tid < 128) {
            const int o = tid & 63, sq = tid >> 6;
            const int i = (o >> 4) * 4 + (o & 3), hh = (o >> 2) & 3;
            const int idx = sq * 16 + i;
            const float s = redf[0][hh][idx] + redf[1][hh][idx] +
                            redf[2][hh][idx] + redf[3][hh][idx];
            part[(size_t)blockIdx.x * 128 + sq * 64 + o] = s;
        }
    } else {
        if (tid < 256) {
            const int o = tid & 127, sq = tid >> 7;
            const int i = (o >> 4) * 4 + (o & 3), hh = (o >> 2) & 3;
            const int idx = sq * 32 + i;
            const float s = redf[0][hh][idx] + redf[1][hh][idx] +
                            redf[2][hh][idx] + redf[3][hh][idx];
            part[(size_t)blockIdx.x * 256 + sq * 128 + o] = s;
        }
    }
}

// ---------------------------------------------------------------------------
// finalize2: reduce chain<2> partials (2048 x [s64|q64]) -> A2/c2; emit
// folded bf16 W2 A-frags.
// ---------------------------------------------------------------------------
__global__ __launch_bounds__(512) void finalize2_kernel(const float* __restrict__ part,
                                                        const float* __restrict__ w1g,
                                                        const float* __restrict__ g1,
                                                        const float* __restrict__ bt1,
                                                        short* __restrict__ wf2f,
                                                        float* __restrict__ c2)
{
    __shared__ double tot[512];
    __shared__ float As[64];
    const int tid = threadIdx.x;
    const int j = tid & 127, r = tid >> 7;    // 4 reducers per stat
    double s = 0.0;
    for (int blk = r; blk < 2048; blk += 4) s += (double)part[(size_t)blk * 128 + j];
    tot[tid] = s;
    __syncthreads();
    if (tid < 128) tot[tid] = tot[tid] + tot[128 + tid] + tot[256 + tid] + tot[384 + tid];
    __syncthreads();
    if (tid < 64) {
        const double mean = tot[tid] / (double)MTOT;
        double var = tot[64 + tid] / (double)MTOT - mean * mean;
        if (var < 0.0) var = 0.0;
        const double A = (double)g1[tid] / sqrt(var + 1e-5);
        As[tid] = (float)A;
        c2[tid] = (float)((double)bt1[tid] - A * mean);
    }
    __syncthreads();
    {
        const int f = tid >> 6, l = tid & 63;
        const int o = (f >> 1) * 16 + (l & 15);
        const int kb = (f & 1) * 32 + (l >> 4) * 8;
#pragma unroll
        for (int j8 = 0; j8 < 8; ++j8)
            wf2f[tid * 8 + j8] = (short)f2bf(As[o] * w1g[o * 64 + kb + j8]);
    }
}

// ---------------------------------------------------------------------------
// finalize3: reduce chain<3> partials (2048 x [s128|q128]) -> A3/c3.
// ---------------------------------------------------------------------------
__global__ __launch_bounds__(512) void finalize3_kernel(const float* __restrict__ part,
                                                        const float* __restrict__ g2,
                                                        const float* __restrict__ bt2,
                                                        float* __restrict__ A3,
                                                        float* __restrict__ c3)
{
    __shared__ double tot[512];
    const int tid = threadIdx.x;
    const int j = tid & 255, r = tid >> 8;    // 2 reducers per stat
    double s = 0.0;
    for (int blk = r; blk < 2048; blk += 2) s += (double)part[(size_t)blk * 256 + j];
    tot[tid] = s;
    __syncthreads();
    if (tid < 256) tot[tid] = tot[tid] + tot[256 + tid];
    __syncthreads();
    if (tid < 128) {
        const double mean = tot[tid] / (double)MTOT;
        double var = tot[128 + tid] / (double)MTOT - mean * mean;
        if (var < 0.0) var = 0.0;
        const double A = (double)g2[tid] / sqrt(var + 1e-5);
        A3[tid] = (float)A;
        c3[tid] = (float)((double)bt2[tid] - A * mean);
    }
}

// ---------------------------------------------------------------------------
// final_out: in-place out = relu(A3*gmax + c3) over (16384 groups x 128 ch).
// ---------------------------------------------------------------------------
__global__ __launch_bounds__(256) void final_out_kernel(float* __restrict__ outF,
                                                        const float* __restrict__ A3,
                                                        const float* __restrict__ c3)
{
    __shared__ float As[128], Cs[128];
    const int tid = threadIdx.x;
    if (tid < 128) { As[tid] = A3[tid]; Cs[tid] = c3[tid]; }
    __syncthreads();
    const int idx = (int)blockIdx.x * 256 + tid;      // f4 index, total 524288
    f4 val = *reinterpret_cast<f4*>(&outF[(size_t)idx * 4]);
    const int chb = (idx * 4) & 127;
#pragma unroll
    for (int jj = 0; jj < 4; ++jj)
        val.v[jj] = fmaxf(fmaf(As[chb + jj], val.v[jj], Cs[chb + jj]), 0.f);
    *reinterpret_cast<f4*>(&outF[(size_t)idx * 4]) = val;
}

// ---------------------------------------------------------------------------
extern "C" void kernel_launch(void* const* d_in, const int* in_sizes, int n_in,
                              void* d_out, int out_size, void* d_ws, size_t ws_size,
                              hipStream_t stream)
{
    const float* xyz  = (const float*)d_in[0];
    const float* feat = (const float*)d_in[1];
    const float* w0  = (const float*)d_in[2];
    const float* g0  = (const float*)d_in[4];
    const float* bt0 = (const float*)d_in[5];
    const float* w1  = (const float*)d_in[6];
    const float* g1  = (const float*)d_in[8];
    const float* bt1 = (const float*)d_in[9];
    const float* w2  = (const float*)d_in[10];
    const float* g2  = (const float*)d_in[12];
    const float* bt2 = (const float*)d_in[13];

    float* out    = (float*)d_out;
    float* newxyz = out;                 // (16,1024,3)
    float* outF   = out + BB * SS * 3;   // (16,1024,128) — gmax then final

    float* wsf  = (float*)d_ws;
    float* v    = wsf;                         // 3145728 floats
    float* part = wsf + 6ull * MTOT;           // 688128 (moments / stat partials)
    float* c1   = part + 688128;               // 64
    float* c2   = c1 + 64;                     // 64
    float* A3   = c2 + 64;                     // 128
    float* c3   = A3 + 128;                    // 128
    short* wf1  = (short*)(c3 + 128);          // 2048 shorts (4 frags)
    short* wf2r = wf1 + 2048;                  // 4096 shorts (8 frags, raw)
    short* wf2f = wf2r + 4096;                 // 4096 shorts (8 frags, folded)
    short* wf3  = wf2f + 4096;                 // 8192 shorts (16 frags, raw)

    prep_kernel<<<dim3(1), dim3(512), 0, stream>>>(w1, w2, wf2r, wf3);
    fps_kernel<<<dim3(BB), dim3(256), 0, stream>>>(xyz, newxyz);
    ball_gather_kernel<<<dim3(4096), dim3(256), 0, stream>>>(xyz, feat, newxyz, v, part);
    finalize1_kernel<<<dim3(1), dim3(512), 0, stream>>>(part, w0, g0, bt0, wf1, c1);

    chain_kernel<2><<<dim3(2048), dim3(256), 0, stream>>>(v, wf1, c1, wf2r, nullptr,
                                                          nullptr, part, nullptr, 2);
    finalize2_kernel<<<dim3(1), dim3(512), 0, stream>>>(part, w1, g1, bt1, wf2f, c2);

    chain_kernel<3><<<dim3(2048), dim3(256), 0, stream>>>(v, wf1, c1, wf2f, c2,
                                                          wf3, part, outF, 2);
    finalize3_kernel<<<dim3(1), dim3(512), 0, stream>>>(part, g2, bt2, A3, c3);
    final_out_kernel<<<dim3(2048), dim3(256), 0, stream>>>(outF, A3, c3);
}

// Round 10
// 1236.103 us; speedup vs baseline: 3.8468x; 1.5391x over previous
//
#include <hip/hip_runtime.h>
#include <math.h>

// Problem constants
#define BB 16
#define NN 8192
#define SS 1024
#define GG 32
#define MTOT (BB*SS*GG)   // 524288
// MLP: 6 -> 64 -> 64 -> 128

struct alignas(16) f4 { float v[4]; };

typedef __attribute__((ext_vector_type(8))) short bfrag;   // 8 bf16 = 4 VGPR
typedef __attribute__((ext_vector_type(4))) float facc;    // 4 f32 acc

#define MFMA16(a, b, c) __builtin_amdgcn_mfma_f32_16x16x32_bf16(a, b, c, 0, 0, 0)

__device__ __forceinline__ unsigned short f2bf(float f) {
    const unsigned u = __float_as_uint(f);
    return (unsigned short)((u + 0x7FFFu + ((u >> 16) & 1u)) >> 16);
}
__device__ __forceinline__ unsigned packbf(float lo, float hi) {
    return (unsigned)f2bf(lo) | ((unsigned)f2bf(hi) << 16);
}

template<int CTRL>
__device__ __forceinline__ int dppmov(int x) {
    return __builtin_amdgcn_update_dpp(x, x, CTRL, 0xF, 0xF, true);
}
// one u64 max-reduce level via DPP permutation of (hi,lo)
template<int CTRL>
__device__ __forceinline__ void dlevel(int& hi, int& lo) {
    const int oh = dppmov<CTRL>(hi);
    const int ol = dppmov<CTRL>(lo);
    const unsigned long long o =
        ((unsigned long long)(unsigned)oh << 32) | (unsigned)ol;
    const unsigned long long c =
        ((unsigned long long)(unsigned)hi << 32) | (unsigned)lo;
    if (o > c) { hi = oh; lo = ol; }
}

// ---------------------------------------------------------------------------
// FPS — round-8 version verbatim (passed, 917 us). Scalar __f*_rn distance
// math ONLY (packed-f32 variants failed twice with identical wrong output —
// dead end, do not revisit). One barrier/step; DPP ROW_ROR reduce.
// ---------------------------------------------------------------------------
__global__ __launch_bounds__(256) void fps_kernel(const float* __restrict__ xyz,
                                                  float* __restrict__ newxyz)
{
    __shared__ float lx[NN], ly[NN], lz[NN];            // 96 KB
    __shared__ unsigned long long slots[2][4];
    const int b = blockIdx.x;
    const int t = threadIdx.x;
    const int wave = t >> 6, lane = t & 63;
    const float* base = xyz + (size_t)b * NN * 3;

    float px[32], py[32], pz[32], dd[32];
#pragma unroll
    for (int k = 0; k < 32; ++k) {
        const int p = (k << 8) + t;
        const float x = base[p * 3 + 0];
        const float y = base[p * 3 + 1];
        const float z = base[p * 3 + 2];
        px[k] = x; py[k] = y; pz[k] = z; dd[k] = 1e10f;
        lx[p] = x; ly[p] = y; lz[p] = z;
    }
    __syncthreads();

    int far = 0;
    float* outb = newxyz + (size_t)b * SS * 3;
    for (int s = 0; s < SS; ++s) {
        const float cx = lx[far], cy = ly[far], cz = lz[far];
        if (t == 0) {
            outb[s * 3 + 0] = cx;
            outb[s * 3 + 1] = cy;
            outb[s * 3 + 2] = cz;
        }
        float bf = -1.f;
        unsigned binv = 0u;
#pragma unroll
        for (int k = 0; k < 32; ++k) {
            const float dx = __fsub_rn(px[k], cx);
            const float dy = __fsub_rn(py[k], cy);
            const float dz = __fsub_rn(pz[k], cz);
            const float d  = __fadd_rn(__fadd_rn(__fmul_rn(dx, dx), __fmul_rn(dy, dy)),
                                       __fmul_rn(dz, dz));
            const float nd = fminf(dd[k], d);
            dd[k] = nd;
            if (nd > bf) {                         // strict > keeps lowest k
                bf = nd;
                binv = 0xFFFFFFFFu - (unsigned)((k << 8) + t);
            }
        }

        int hi = __float_as_int(bf);   // bf >= 0 -> monotone bit pattern
        int lo = (int)binv;
        dlevel<0x121>(hi, lo);         // ROW_ROR:1
        dlevel<0x122>(hi, lo);         // ROW_ROR:2
        dlevel<0x124>(hi, lo);         // ROW_ROR:4
        dlevel<0x128>(hi, lo);         // ROW_ROR:8  -> max over each 16-row
        {
            const int oh = __shfl_xor(hi, 16), ol = __shfl_xor(lo, 16);
            const unsigned long long o =
                ((unsigned long long)(unsigned)oh << 32) | (unsigned)ol;
            const unsigned long long c =
                ((unsigned long long)(unsigned)hi << 32) | (unsigned)lo;
            if (o > c) { hi = oh; lo = ol; }
        }
        {
            const int oh = __shfl_xor(hi, 32), ol = __shfl_xor(lo, 32);
            const unsigned long long o =
                ((unsigned long long)(unsigned)oh << 32) | (unsigned)ol;
            const unsigned long long c =
                ((unsigned long long)(unsigned)hi << 32) | (unsigned)lo;
            if (o > c) { hi = oh; lo = ol; }
        }

        if (lane == 0)
            slots[s & 1][wave] =
                ((unsigned long long)(unsigned)hi << 32) | (unsigned)lo;
        __syncthreads();
        unsigned long long g = slots[s & 1][0];
#pragma unroll
        for (int w = 1; w < 4; ++w) {
            const unsigned long long o = slots[s & 1][w];
            g = (o > g) ? o : g;
        }
        far = (int)(0xFFFFFFFFu - (unsigned)(g & 0xFFFFFFFFull));
    }
}

// ---------------------------------------------------------------------------
// ball query + gather + v first/second moments (round-8 verbatim).
// ---------------------------------------------------------------------------
__global__ __launch_bounds__(256) void ball_gather_kernel(const float* __restrict__ xyz,
                                                          const float* __restrict__ feat,
                                                          const float* __restrict__ newxyz,
                                                          float* __restrict__ v,
                                                          float* __restrict__ part1)
{
    const int wid  = (int)((blockIdx.x * 256 + threadIdx.x) >> 6);
    const int lane = threadIdx.x & 63;
    if (wid >= BB * SS) return;
    const int b = wid >> 10;

    const float cx = newxyz[wid * 3 + 0];
    const float cy = newxyz[wid * 3 + 1];
    const float cz = newxyz[wid * 3 + 2];
    const float* xb = xyz + (size_t)b * NN * 3;
    const float* fb = feat + (size_t)b * NN * 3;
    const size_t mbase = (size_t)wid * GG;

    float mS[6];
    float mP[36];
#pragma unroll
    for (int c = 0; c < 6; ++c) mS[c] = 0.f;
#pragma unroll
    for (int c = 0; c < 36; ++c) mP[c] = 0.f;

    int cnt = 0, firstp = -1;
    for (int base = 0; base < NN && cnt < GG; base += 64) {
        const int p = base + lane;
        const float x = xb[p * 3 + 0], y = xb[p * 3 + 1], z = xb[p * 3 + 2];
        const float dx = __fsub_rn(cx, x);
        const float dy = __fsub_rn(cy, y);
        const float dz = __fsub_rn(cz, z);
        const float d  = __fadd_rn(__fadd_rn(__fmul_rn(dx, dx), __fmul_rn(dy, dy)),
                                   __fmul_rn(dz, dz));
        const bool hit = (d <= 0.04f);
        const unsigned long long m = __ballot(hit);
        if (firstp < 0 && m != 0ull) firstp = base + (int)__builtin_ctzll(m);
        const int pos = cnt + (int)__popcll(m & ((1ull << lane) - 1ull));
        if (hit && pos < GG) {
            const size_t mm = mbase + pos;
            float a[6];
            a[0] = __fsub_rn(x, cx);
            a[1] = __fsub_rn(y, cy);
            a[2] = __fsub_rn(z, cz);
            a[3] = fb[p * 3 + 0];
            a[4] = fb[p * 3 + 1];
            a[5] = fb[p * 3 + 2];
#pragma unroll
            for (int c = 0; c < 6; ++c) {
                v[(size_t)c * MTOT + mm] = a[c];
                mS[c] += a[c];
#pragma unroll
                for (int dch = 0; dch < 6; ++dch)
                    mP[c * 6 + dch] = fmaf(a[c], a[dch], mP[c * 6 + dch]);
            }
        }
        cnt += (int)__popcll(m);
    }
    if (cnt < GG) {
        const int p = firstp;
        const float x = xb[p * 3 + 0], y = xb[p * 3 + 1], z = xb[p * 3 + 2];
        float a[6];
        a[0] = __fsub_rn(x, cx);
        a[1] = __fsub_rn(y, cy);
        a[2] = __fsub_rn(z, cz);
        a[3] = fb[p * 3 + 0];
        a[4] = fb[p * 3 + 1];
        a[5] = fb[p * 3 + 2];
        for (int j = cnt + lane; j < GG; j += 64) {
            const size_t mm = mbase + j;
#pragma unroll
            for (int c = 0; c < 6; ++c) {
                v[(size_t)c * MTOT + mm] = a[c];
                mS[c] += a[c];
#pragma unroll
                for (int dch = 0; dch < 6; ++dch)
                    mP[c * 6 + dch] = fmaf(a[c], a[dch], mP[c * 6 + dch]);
            }
        }
    }
#pragma unroll
    for (int off = 1; off < 64; off <<= 1) {
#pragma unroll
        for (int c = 0; c < 6; ++c) mS[c] += __shfl_xor(mS[c], off);
#pragma unroll
        for (int c = 0; c < 36; ++c) mP[c] += __shfl_xor(mP[c], off);
    }
    if (lane == 0) {
        float* row = part1 + (size_t)wid * 42;
#pragma unroll
        for (int c = 0; c < 6; ++c) row[c] = mS[c];
#pragma unroll
        for (int c = 0; c < 36; ++c) row[6 + c] = mP[c];
    }
}

// ---------------------------------------------------------------------------
// finalize1 (+prep merged, 1024 thr): build raw bf16 W2/W3 A-frags; reduce v
// moments (24 reducers/moment, unroll-4); analytic BN1; emit folded W1 frags
// + c1. Frag layout: entry (f, lane l): A[o][k], o=(f>>1)*16+(l&15),
// k=(f&1)*32+(l>>4)*8+j. Stored flat [(f*64+l)*8+j].
// ---------------------------------------------------------------------------
__global__ __launch_bounds__(1024) void finalize1_kernel(const float* __restrict__ part1,
                                                         const float* __restrict__ w0,
                                                         const float* __restrict__ g0,
                                                         const float* __restrict__ bt0,
                                                         const float* __restrict__ w1g,
                                                         const float* __restrict__ w2g,
                                                         short* __restrict__ wf1,
                                                         float* __restrict__ c1,
                                                         short* __restrict__ wf2r,
                                                         short* __restrict__ wf3r)
{
    const int tid = threadIdx.x;
    // --- prep: raw W2 frags (512 entries) ---
    if (tid < 512) {
        const int f = tid >> 6, l = tid & 63;
        const int o = (f >> 1) * 16 + (l & 15);
        const int kb = (f & 1) * 32 + (l >> 4) * 8;
#pragma unroll
        for (int j = 0; j < 8; ++j)
            wf2r[tid * 8 + j] = (short)f2bf(w1g[o * 64 + kb + j]);
    }
    // --- prep: raw W3 frags (1024 entries, one per thread) ---
    {
        const int f = tid >> 6, l = tid & 63;
        const int o = (f >> 1) * 16 + (l & 15);
        const int kb = (f & 1) * 32 + (l >> 4) * 8;
#pragma unroll
        for (int j = 0; j < 8; ++j)
            wf3r[tid * 8 + j] = (short)f2bf(w2g[o * 64 + kb + j]);
    }

    __shared__ double red[1008];
    __shared__ double tot[42];
    __shared__ float Asf[64];
    if (tid < 1008) {
        const int j = tid % 42, r = tid / 42;   // 24 reducers per moment
        double s = 0.0;
#pragma unroll 4
        for (int i = r; i < BB * SS; i += 24) s += (double)part1[(size_t)i * 42 + j];
        red[tid] = s;
    }
    __syncthreads();
    if (tid < 42) {
        double s = 0.0;
        for (int r = 0; r < 24; ++r) s += red[r * 42 + tid];
        tot[tid] = s / (double)MTOT;
    }
    __syncthreads();
    if (tid < 64) {
        double m1 = 0.0;
        for (int c = 0; c < 6; ++c) m1 += (double)w0[tid * 6 + c] * tot[c];
        double e2 = 0.0;
        for (int c = 0; c < 6; ++c)
            for (int d = 0; d < 6; ++d)
                e2 += (double)w0[tid * 6 + c] * (double)w0[tid * 6 + d] * tot[6 + c * 6 + d];
        double var = e2 - m1 * m1;
        if (var < 0.0) var = 0.0;
        const double A = (double)g0[tid] / sqrt(var + 1e-5);
        Asf[tid] = (float)A;
        c1[tid] = (float)((double)bt0[tid] - A * m1);
    }
    __syncthreads();
    if (tid < 256) {
        const int l = tid & 63;
        const int o = (tid >> 6) * 16 + (l & 15);
        const int h = l >> 4;
#pragma unroll
        for (int j = 0; j < 8; ++j) {
            const float val = (h == 0 && j < 6) ? Asf[o] * w0[o * 6 + j] : 0.f;
            wf1[tid * 8 + j] = (short)f2bf(val);
        }
    }
}

// ---------------------------------------------------------------------------
// MFMA chain kernel (round-6/8 design, verbatim). 256 thr = 4 waves; wave
// processes one 32-pt group per tile-iter as 2 m-steps of 16.
// PHASE 2: stats of x2_nb. PHASE 3: stats of x3_nb + pre-BN3 group max.
// ---------------------------------------------------------------------------
template<int PHASE>
__global__ __launch_bounds__(256, 2) void chain_kernel(
    const float* __restrict__ v,
    const short* __restrict__ wf1, const float* __restrict__ c1,
    const short* __restrict__ wf2, const float* __restrict__ c2,
    const short* __restrict__ wf3,
    float* __restrict__ part, float* __restrict__ gmax, int tpb)
{
    __shared__ alignas(16) unsigned Hu1[4][16][36];
    __shared__ alignas(16) unsigned Hu2[(PHASE == 3) ? 4 : 1][16][36];
    __shared__ alignas(16) short w3l[(PHASE == 3) ? 8192 : 8];
    __shared__ alignas(16) float gm[(PHASE == 3) ? 4 : 1][128][20];
    __shared__ float redf[4][4][64];

    const int tid = threadIdx.x;
    const int w = tid >> 6, l = tid & 63;
    const int mcol = l & 15, h = l >> 4;

    if constexpr (PHASE == 3) {
        const unsigned* src = (const unsigned*)wf3;
        unsigned* dst = (unsigned*)w3l;
        for (int i = tid; i < 4096; i += 256) dst[i] = src[i];
    }
    __syncthreads();

    bfrag a1[4];
#pragma unroll
    for (int t = 0; t < 4; ++t) a1[t] = *(const bfrag*)&wf1[(t * 64 + l) * 8];
    bfrag a2[8];
#pragma unroll
    for (int f = 0; f < 8; ++f) a2[f] = *(const bfrag*)&wf2[(f * 64 + l) * 8];
    float c1v[16];
#pragma unroll
    for (int t = 0; t < 4; ++t)
#pragma unroll
        for (int r = 0; r < 4; ++r) c1v[t * 4 + r] = c1[t * 16 + h * 4 + r];
    float c2v[16];
    if constexpr (PHASE == 3) {
#pragma unroll
        for (int t = 0; t < 4; ++t)
#pragma unroll
            for (int r = 0; r < 4; ++r) c2v[t * 4 + r] = c2[t * 16 + h * 4 + r];
    }

    constexpr int NS = (PHASE == 3) ? 32 : 16;
    float sA[NS], qA[NS];
#pragma unroll
    for (int i = 0; i < NS; ++i) { sA[i] = 0.f; qA[i] = 0.f; }

    const facc zf = {0.f, 0.f, 0.f, 0.f};

    for (int ti = 0; ti < tpb; ++ti) {
        const int tile = blockIdx.x * tpb + ti;
        float mx[(PHASE == 3) ? 32 : 1];
        if constexpr (PHASE == 3) {
#pragma unroll
            for (int i = 0; i < 32; ++i) mx[i] = -3.0e38f;
        }

#pragma unroll
        for (int st = 0; st < 2; ++st) {
            const int mg = tile * 128 + w * 32 + st * 16 + mcol;

            bfrag bv;
#pragma unroll
            for (int j = 0; j < 8; ++j) bv[j] = 0;
            if (h == 0) {
#pragma unroll
                for (int j = 0; j < 6; ++j)
                    bv[j] = (short)f2bf(v[(size_t)j * MTOT + mg]);
            }
            facc x1[4];
#pragma unroll
            for (int t = 0; t < 4; ++t) x1[t] = MFMA16(a1[t], bv, zf);
#pragma unroll
            for (int t = 0; t < 4; ++t)
#pragma unroll
                for (int rr = 0; rr < 2; ++rr)
                    Hu1[w][mcol][t * 8 + h * 2 + rr] = packbf(
                        fmaxf(x1[t][2 * rr]     + c1v[t * 4 + 2 * rr],     0.f),
                        fmaxf(x1[t][2 * rr + 1] + c1v[t * 4 + 2 * rr + 1], 0.f));

            const bfrag b0 = *(const bfrag*)&Hu1[w][mcol][h * 4];
            const bfrag b1 = *(const bfrag*)&Hu1[w][mcol][16 + h * 4];

            if constexpr (PHASE == 2) {
#pragma unroll
                for (int t = 0; t < 4; ++t) {
                    facc a = MFMA16(a2[2 * t], b0, zf);
                    a = MFMA16(a2[2 * t + 1], b1, a);
#pragma unroll
                    for (int r = 0; r < 4; ++r) {
                        const float x = a[r];
                        sA[t * 4 + r] += x;
                        qA[t * 4 + r] = fmaf(x, x, qA[t * 4 + r]);
                    }
                }
            } else {
#pragma unroll
                for (int t = 0; t < 4; ++t) {
                    facc a = MFMA16(a2[2 * t], b0, zf);
                    a = MFMA16(a2[2 * t + 1], b1, a);
#pragma unroll
                    for (int rr = 0; rr < 2; ++rr)
                        Hu2[w][mcol][t * 8 + h * 2 + rr] = packbf(
                            fmaxf(a[2 * rr]     + c2v[t * 4 + 2 * rr],     0.f),
                            fmaxf(a[2 * rr + 1] + c2v[t * 4 + 2 * rr + 1], 0.f));
                }
                const bfrag d0 = *(const bfrag*)&Hu2[w][mcol][h * 4];
                const bfrag d1 = *(const bfrag*)&Hu2[w][mcol][16 + h * 4];
#pragma unroll
                for (int t3 = 0; t3 < 8; ++t3) {
                    const bfrag wa = *(const bfrag*)&w3l[((t3 * 2 + 0) * 64 + l) * 8];
                    const bfrag wb = *(const bfrag*)&w3l[((t3 * 2 + 1) * 64 + l) * 8];
                    facc a = MFMA16(wa, d0, zf);
                    a = MFMA16(wb, d1, a);
#pragma unroll
                    for (int r = 0; r < 4; ++r) {
                        const float x = a[r];
                        const int i = t3 * 4 + r;
                        sA[i] += x;
                        qA[i] = fmaf(x, x, qA[i]);
                        mx[i] = fmaxf(mx[i], x);
                    }
                }
            }
        }

        if constexpr (PHASE == 3) {
#pragma unroll
            for (int t3 = 0; t3 < 8; ++t3)
#pragma unroll
                for (int r = 0; r < 4; ++r)
                    gm[w][t3 * 16 + h * 4 + r][mcol] = mx[t3 * 4 + r];
            float m0 = -3.0e38f, m1 = -3.0e38f;
#pragma unroll
            for (int c4i = 0; c4i < 4; ++c4i) {
                const facc v0 = *(const facc*)&gm[w][2 * l][c4i * 4];
                const facc v1 = *(const facc*)&gm[w][2 * l + 1][c4i * 4];
#pragma unroll
                for (int jj = 0; jj < 4; ++jj) {
                    m0 = fmaxf(m0, v0[jj]);
                    m1 = fmaxf(m1, v1[jj]);
                }
            }
            const int g = tile * 4 + w;
            gmax[(size_t)g * 128 + 2 * l]     = m0;
            gmax[(size_t)g * 128 + 2 * l + 1] = m1;
        }
    }

#pragma unroll
    for (int off = 1; off < 16; off <<= 1) {
#pragma unroll
        for (int i = 0; i < NS; ++i) {
            sA[i] += __shfl_xor(sA[i], off);
            qA[i] += __shfl_xor(qA[i], off);
        }
    }
    __syncthreads();
    if (mcol == 0) {
#pragma unroll
        for (int i = 0; i < NS; ++i) {
            redf[w][h][i] = sA[i];
            redf[w][h][NS + i] = qA[i];
        }
    }
    __syncthreads();
    if constexpr (PHASE == 2) {
        if (tid < 128) {
            const int o = tid & 63, sq = tid >> 6;
            const int i = (o >> 4) * 4 + (o & 3), hh = (o >> 2) & 3;
            const int idx = sq * 16 + i;
            const float s = redf[0][hh][idx] + redf[1][hh][idx] +
                            redf[2][hh][idx] + redf[3][hh][idx];
            part[(size_t)blockIdx.x * 128 + sq * 64 + o] = s;
        }
    } else {
        if (tid < 256) {
            const int o = tid & 127, sq = tid >> 7;
            const int i = (o >> 4) * 4 + (o & 3), hh = (o >> 2) & 3;
            const int idx = sq * 32 + i;
            const float s = redf[0][hh][idx] + redf[1][hh][idx] +
                            redf[2][hh][idx] + redf[3][hh][idx];
            part[(size_t)blockIdx.x * 256 + sq * 128 + o] = s;
        }
    }
}

// ---------------------------------------------------------------------------
// finalize2 (1024 thr, 8 reducers/stat, unroll-4): chain<2> partials
// (2048 x [s64|q64]) -> A2/c2; emit folded bf16 W2 A-frags.
// ---------------------------------------------------------------------------
__global__ __launch_bounds__(1024) void finalize2_kernel(const float* __restrict__ part,
                                                         const float* __restrict__ w1g,
                                                         const float* __restrict__ g1,
                                                         const float* __restrict__ bt1,
                                                         short* __restrict__ wf2f,
                                                         float* __restrict__ c2)
{
    __shared__ double tot[1024];
    __shared__ float As[64];
    const int tid = threadIdx.x;
    const int j = tid & 127, r = tid >> 7;    // 8 reducers per stat
    double s = 0.0;
#pragma unroll 4
    for (int blk = r; blk < 2048; blk += 8) s += (double)part[(size_t)blk * 128 + j];
    tot[tid] = s;
    __syncthreads();
    if (tid < 128) {
        double t = 0.0;
#pragma unroll
        for (int g = 0; g < 8; ++g) t += tot[g * 128 + tid];
        tot[tid] = t;
    }
    __syncthreads();
    if (tid < 64) {
        const double mean = tot[tid] / (double)MTOT;
        double var = tot[64 + tid] / (double)MTOT - mean * mean;
        if (var < 0.0) var = 0.0;
        const double A = (double)g1[tid] / sqrt(var + 1e-5);
        As[tid] = (float)A;
        c2[tid] = (float)((double)bt1[tid] - A * mean);
    }
    __syncthreads();
    if (tid < 512) {
        const int f = tid >> 6, l = tid & 63;
        const int o = (f >> 1) * 16 + (l & 15);
        const int kb = (f & 1) * 32 + (l >> 4) * 8;
#pragma unroll
        for (int j8 = 0; j8 < 8; ++j8)
            wf2f[tid * 8 + j8] = (short)f2bf(As[o] * w1g[o * 64 + kb + j8]);
    }
}

// ---------------------------------------------------------------------------
// finalize3 (1024 thr, 4 reducers/stat, unroll-4): chain<3> partials
// (2048 x [s128|q128]) -> A3/c3.
// ---------------------------------------------------------------------------
__global__ __launch_bounds__(1024) void finalize3_kernel(const float* __restrict__ part,
                                                         const float* __restrict__ g2,
                                                         const float* __restrict__ bt2,
                                                         float* __restrict__ A3,
                                                         float* __restrict__ c3)
{
    __shared__ double tot[1024];
    const int tid = threadIdx.x;
    const int j = tid & 255, r = tid >> 8;    // 4 reducers per stat
    double s = 0.0;
#pragma unroll 4
    for (int blk = r; blk < 2048; blk += 4) s += (double)part[(size_t)blk * 256 + j];
    tot[tid] = s;
    __syncthreads();
    if (tid < 256) {
        const double t = tot[tid] + tot[256 + tid] + tot[512 + tid] + tot[768 + tid];
        tot[tid] = t;
    }
    __syncthreads();
    if (tid < 128) {
        const double mean = tot[tid] / (double)MTOT;
        double var = tot[128 + tid] / (double)MTOT - mean * mean;
        if (var < 0.0) var = 0.0;
        const double A = (double)g2[tid] / sqrt(var + 1e-5);
        A3[tid] = (float)A;
        c3[tid] = (float)((double)bt2[tid] - A * mean);
    }
}

// ---------------------------------------------------------------------------
// final_out: in-place out = relu(A3*gmax + c3) over (16384 groups x 128 ch).
// ---------------------------------------------------------------------------
__global__ __launch_bounds__(256) void final_out_kernel(float* __restrict__ outF,
                                                        const float* __restrict__ A3,
                                                        const float* __restrict__ c3)
{
    __shared__ float As[128], Cs[128];
    const int tid = threadIdx.x;
    if (tid < 128) { As[tid] = A3[tid]; Cs[tid] = c3[tid]; }
    __syncthreads();
    const int idx = (int)blockIdx.x * 256 + tid;      // f4 index, total 524288
    f4 val = *reinterpret_cast<f4*>(&outF[(size_t)idx * 4]);
    const int chb = (idx * 4) & 127;
#pragma unroll
    for (int jj = 0; jj < 4; ++jj)
        val.v[jj] = fmaxf(fmaf(As[chb + jj], val.v[jj], Cs[chb + jj]), 0.f);
    *reinterpret_cast<f4*>(&outF[(size_t)idx * 4]) = val;
}

// ---------------------------------------------------------------------------
extern "C" void kernel_launch(void* const* d_in, const int* in_sizes, int n_in,
                              void* d_out, int out_size, void* d_ws, size_t ws_size,
                              hipStream_t stream)
{
    const float* xyz  = (const float*)d_in[0];
    const float* feat = (const float*)d_in[1];
    const float* w0  = (const float*)d_in[2];
    const float* g0  = (const float*)d_in[4];
    const float* bt0 = (const float*)d_in[5];
    const float* w1  = (const float*)d_in[6];
    const float* g1  = (const float*)d_in[8];
    const float* bt1 = (const float*)d_in[9];
    const float* w2  = (const float*)d_in[10];
    const float* g2  = (const float*)d_in[12];
    const float* bt2 = (const float*)d_in[13];

    float* out    = (float*)d_out;
    float* newxyz = out;                 // (16,1024,3)
    float* outF   = out + BB * SS * 3;   // (16,1024,128) — gmax then final

    float* wsf  = (float*)d_ws;
    float* v    = wsf;                         // 3145728 floats
    float* part = wsf + 6ull * MTOT;           // 688128 (moments / stat partials)
    float* c1   = part + 688128;               // 64
    float* c2   = c1 + 64;                     // 64
    float* A3   = c2 + 64;                     // 128
    float* c3   = A3 + 128;                    // 128
    short* wf1  = (short*)(c3 + 128);          // 2048 shorts (4 frags)
    short* wf2r = wf1 + 2048;                  // 4096 shorts (8 frags, raw)
    short* wf2f = wf2r + 4096;                 // 4096 shorts (8 frags, folded)
    short* wf3  = wf2f + 4096;                 // 8192 shorts (16 frags, raw)

    fps_kernel<<<dim3(BB), dim3(256), 0, stream>>>(xyz, newxyz);
    ball_gather_kernel<<<dim3(4096), dim3(256), 0, stream>>>(xyz, feat, newxyz, v, part);
    finalize1_kernel<<<dim3(1), dim3(1024), 0, stream>>>(part, w0, g0, bt0, w1, w2,
                                                         wf1, c1, wf2r, wf3);

    chain_kernel<2><<<dim3(2048), dim3(256), 0, stream>>>(v, wf1, c1, wf2r, nullptr,
                                                          nullptr, part, nullptr, 2);
    finalize2_kernel<<<dim3(1), dim3(1024), 0, stream>>>(part, w1, g1, bt1, wf2f, c2);

    chain_kernel<3><<<dim3(2048), dim3(256), 0, stream>>>(v, wf1, c1, wf2f, c2,
                                                          wf3, part, outF, 2);
    finalize3_kernel<<<dim3(1), dim3(1024), 0, stream>>>(part, g2, bt2, A3, c3);
    final_out_kernel<<<dim3(2048), dim3(256), 0, stream>>>(outF, A3, c3);
}

// Round 11
// 1227.700 us; speedup vs baseline: 3.8731x; 1.0068x over previous
//
#include <hip/hip_runtime.h>
#include <math.h>

// Problem constants
#define BB 16
#define NN 8192
#define SS 1024
#define GG 32
#define MTOT (BB*SS*GG)   // 524288
// MLP: 6 -> 64 -> 64 -> 128

struct alignas(16) f4 { float v[4]; };

typedef __attribute__((ext_vector_type(8))) short bfrag;   // 8 bf16 = 4 VGPR
typedef __attribute__((ext_vector_type(4))) float facc;    // 4 f32 acc

#define MFMA16(a, b, c) __builtin_amdgcn_mfma_f32_16x16x32_bf16(a, b, c, 0, 0, 0)

__device__ __forceinline__ unsigned short f2bf(float f) {
    const unsigned u = __float_as_uint(f);
    return (unsigned short)((u + 0x7FFFu + ((u >> 16) & 1u)) >> 16);
}
__device__ __forceinline__ unsigned packbf(float lo, float hi) {
    return (unsigned)f2bf(lo) | ((unsigned)f2bf(hi) << 16);
}

template<int CTRL>
__device__ __forceinline__ int dppmov(int x) {
    return __builtin_amdgcn_update_dpp(x, x, CTRL, 0xF, 0xF, true);
}
// one u64 max-reduce level via DPP permutation of (hi,lo)
template<int CTRL>
__device__ __forceinline__ void dlevel(int& hi, int& lo) {
    const int oh = dppmov<CTRL>(hi);
    const int ol = dppmov<CTRL>(lo);
    const unsigned long long o =
        ((unsigned long long)(unsigned)oh << 32) | (unsigned)ol;
    const unsigned long long c =
        ((unsigned long long)(unsigned)hi << 32) | (unsigned)lo;
    if (o > c) { hi = oh; lo = ol; }
}
// 16-lane-group sum via ROW_ROR rotate-reduce (every lane gets group total)
__device__ __forceinline__ float dppadd16(float x) {
    x += __int_as_float(dppmov<0x121>(__float_as_int(x)));   // ROW_ROR:1
    x += __int_as_float(dppmov<0x122>(__float_as_int(x)));   // ROW_ROR:2
    x += __int_as_float(dppmov<0x124>(__float_as_int(x)));   // ROW_ROR:4
    x += __int_as_float(dppmov<0x128>(__float_as_int(x)));   // ROW_ROR:8
    return x;
}

// ---------------------------------------------------------------------------
// FPS. Scalar __f*_rn distance math ONLY (packed-f32 failed twice with
// identical wrong output — dead end, do not revisit). One barrier per step.
// Block reduce: 4 DPP ROW_ROR levels -> every lane holds its 16-row max ->
// lanes l&15==0 publish 16 row winners -> barrier -> all threads tree-scan
// 16 slots (replaces the 2 serial shfl_xor u64 levels of round 8).
// ---------------------------------------------------------------------------
__global__ __launch_bounds__(256) void fps_kernel(const float* __restrict__ xyz,
                                                  float* __restrict__ newxyz)
{
    __shared__ float lx[NN], ly[NN], lz[NN];            // 96 KB
    __shared__ unsigned long long slots[2][16];
    const int b = blockIdx.x;
    const int t = threadIdx.x;
    const int wave = t >> 6, lane = t & 63;
    const float* base = xyz + (size_t)b * NN * 3;

    float px[32], py[32], pz[32], dd[32];
#pragma unroll
    for (int k = 0; k < 32; ++k) {
        const int p = (k << 8) + t;
        const float x = base[p * 3 + 0];
        const float y = base[p * 3 + 1];
        const float z = base[p * 3 + 2];
        px[k] = x; py[k] = y; pz[k] = z; dd[k] = 1e10f;
        lx[p] = x; ly[p] = y; lz[p] = z;
    }
    __syncthreads();

    int far = 0;
    float* outb = newxyz + (size_t)b * SS * 3;
    for (int s = 0; s < SS; ++s) {
        const float cx = lx[far], cy = ly[far], cz = lz[far];
        if (t == 0) {
            outb[s * 3 + 0] = cx;
            outb[s * 3 + 1] = cy;
            outb[s * 3 + 2] = cz;
        }
        float bf = -1.f;
        unsigned binv = 0u;
#pragma unroll
        for (int k = 0; k < 32; ++k) {
            const float dx = __fsub_rn(px[k], cx);
            const float dy = __fsub_rn(py[k], cy);
            const float dz = __fsub_rn(pz[k], cz);
            const float d  = __fadd_rn(__fadd_rn(__fmul_rn(dx, dx), __fmul_rn(dy, dy)),
                                       __fmul_rn(dz, dz));
            const float nd = fminf(dd[k], d);
            dd[k] = nd;
            if (nd > bf) {                         // strict > keeps lowest k
                bf = nd;
                binv = 0xFFFFFFFFu - (unsigned)((k << 8) + t);
            }
        }

        int hi = __float_as_int(bf);   // bf >= 0 -> monotone bit pattern
        int lo = (int)binv;
        dlevel<0x121>(hi, lo);         // ROW_ROR:1
        dlevel<0x122>(hi, lo);         // ROW_ROR:2
        dlevel<0x124>(hi, lo);         // ROW_ROR:4
        dlevel<0x128>(hi, lo);         // ROW_ROR:8  -> every lane: 16-row max

        if ((lane & 15) == 0)
            slots[s & 1][(wave << 2) | (lane >> 4)] =
                ((unsigned long long)(unsigned)hi << 32) | (unsigned)lo;
        __syncthreads();
        const unsigned long long* sl = slots[s & 1];
        unsigned long long m8[8];
#pragma unroll
        for (int i = 0; i < 8; ++i) {
            const unsigned long long a = sl[2 * i], c = sl[2 * i + 1];
            m8[i] = (a > c) ? a : c;
        }
#pragma unroll
        for (int i = 0; i < 4; ++i)
            m8[i] = (m8[2 * i] > m8[2 * i + 1]) ? m8[2 * i] : m8[2 * i + 1];
        m8[0] = (m8[0] > m8[1]) ? m8[0] : m8[1];
        m8[2] = (m8[2] > m8[3]) ? m8[2] : m8[3];
        const unsigned long long g = (m8[0] > m8[2]) ? m8[0] : m8[2];
        far = (int)(0xFFFFFFFFu - (unsigned)(g & 0xFFFFFFFFull));
    }
}

// ---------------------------------------------------------------------------
// ball query + gather + v first/second moments (round-8 verbatim).
// ---------------------------------------------------------------------------
__global__ __launch_bounds__(256) void ball_gather_kernel(const float* __restrict__ xyz,
                                                          const float* __restrict__ feat,
                                                          const float* __restrict__ newxyz,
                                                          float* __restrict__ v,
                                                          float* __restrict__ part1)
{
    const int wid  = (int)((blockIdx.x * 256 + threadIdx.x) >> 6);
    const int lane = threadIdx.x & 63;
    if (wid >= BB * SS) return;
    const int b = wid >> 10;

    const float cx = newxyz[wid * 3 + 0];
    const float cy = newxyz[wid * 3 + 1];
    const float cz = newxyz[wid * 3 + 2];
    const float* xb = xyz + (size_t)b * NN * 3;
    const float* fb = feat + (size_t)b * NN * 3;
    const size_t mbase = (size_t)wid * GG;

    float mS[6];
    float mP[36];
#pragma unroll
    for (int c = 0; c < 6; ++c) mS[c] = 0.f;
#pragma unroll
    for (int c = 0; c < 36; ++c) mP[c] = 0.f;

    int cnt = 0, firstp = -1;
    for (int base = 0; base < NN && cnt < GG; base += 64) {
        const int p = base + lane;
        const float x = xb[p * 3 + 0], y = xb[p * 3 + 1], z = xb[p * 3 + 2];
        const float dx = __fsub_rn(cx, x);
        const float dy = __fsub_rn(cy, y);
        const float dz = __fsub_rn(cz, z);
        const float d  = __fadd_rn(__fadd_rn(__fmul_rn(dx, dx), __fmul_rn(dy, dy)),
                                   __fmul_rn(dz, dz));
        const bool hit = (d <= 0.04f);
        const unsigned long long m = __ballot(hit);
        if (firstp < 0 && m != 0ull) firstp = base + (int)__builtin_ctzll(m);
        const int pos = cnt + (int)__popcll(m & ((1ull << lane) - 1ull));
        if (hit && pos < GG) {
            const size_t mm = mbase + pos;
            float a[6];
            a[0] = __fsub_rn(x, cx);
            a[1] = __fsub_rn(y, cy);
            a[2] = __fsub_rn(z, cz);
            a[3] = fb[p * 3 + 0];
            a[4] = fb[p * 3 + 1];
            a[5] = fb[p * 3 + 2];
#pragma unroll
            for (int c = 0; c < 6; ++c) {
                v[(size_t)c * MTOT + mm] = a[c];
                mS[c] += a[c];
#pragma unroll
                for (int dch = 0; dch < 6; ++dch)
                    mP[c * 6 + dch] = fmaf(a[c], a[dch], mP[c * 6 + dch]);
            }
        }
        cnt += (int)__popcll(m);
    }
    if (cnt < GG) {
        const int p = firstp;
        const float x = xb[p * 3 + 0], y = xb[p * 3 + 1], z = xb[p * 3 + 2];
        float a[6];
        a[0] = __fsub_rn(x, cx);
        a[1] = __fsub_rn(y, cy);
        a[2] = __fsub_rn(z, cz);
        a[3] = fb[p * 3 + 0];
        a[4] = fb[p * 3 + 1];
        a[5] = fb[p * 3 + 2];
        for (int j = cnt + lane; j < GG; j += 64) {
            const size_t mm = mbase + j;
#pragma unroll
            for (int c = 0; c < 6; ++c) {
                v[(size_t)c * MTOT + mm] = a[c];
                mS[c] += a[c];
#pragma unroll
                for (int dch = 0; dch < 6; ++dch)
                    mP[c * 6 + dch] = fmaf(a[c], a[dch], mP[c * 6 + dch]);
            }
        }
    }
#pragma unroll
    for (int off = 1; off < 64; off <<= 1) {
#pragma unroll
        for (int c = 0; c < 6; ++c) mS[c] += __shfl_xor(mS[c], off);
#pragma unroll
        for (int c = 0; c < 36; ++c) mP[c] += __shfl_xor(mP[c], off);
    }
    if (lane == 0) {
        float* row = part1 + (size_t)wid * 42;
#pragma unroll
        for (int c = 0; c < 6; ++c) row[c] = mS[c];
#pragma unroll
        for (int c = 0; c < 36; ++c) row[6 + c] = mP[c];
    }
}

// ---------------------------------------------------------------------------
// reduce1: collapse part1 (16384 x 42) -> red64 (64 x 42). 64 blocks x 256.
// Coalesced float2 row loads, LDS transpose, staged f32 sums (error << tol).
// ---------------------------------------------------------------------------
__global__ __launch_bounds__(256) void reduce1_kernel(const float* __restrict__ part1,
                                                      float* __restrict__ red64)
{
    __shared__ float ldsT[42][260];
    const int tid = threadIdx.x;
    const int row = (int)blockIdx.x * 256 + tid;
    const float* rp = part1 + (size_t)row * 42;
    float r42[42];
#pragma unroll
    for (int i = 0; i < 21; ++i) {
        const float2 v2 = *reinterpret_cast<const float2*>(rp + 2 * i);
        r42[2 * i] = v2.x; r42[2 * i + 1] = v2.y;
    }
#pragma unroll
    for (int c = 0; c < 42; ++c) ldsT[c][tid] = r42[c];
    __syncthreads();
    if (tid < 168) {
        const int c = tid >> 2, r = tid & 3;
        float s = 0.f;
#pragma unroll
        for (int k = 0; k < 64; ++k) s += ldsT[c][r * 64 + k];
        ldsT[c][256 + r] = s;   // pad columns 256..259
    }
    __syncthreads();
    if (tid < 42)
        red64[(size_t)blockIdx.x * 42 + tid] =
            (ldsT[tid][256] + ldsT[tid][257]) + (ldsT[tid][258] + ldsT[tid][259]);
}

// ---------------------------------------------------------------------------
// finalize1 (+prep merged, 1024 thr): build raw bf16 W2/W3 A-frags; reduce
// red64 (64 x 42); analytic BN1; emit folded W1 frags + c1.
// ---------------------------------------------------------------------------
__global__ __launch_bounds__(1024) void finalize1_kernel(const float* __restrict__ red64,
                                                         const float* __restrict__ w0,
                                                         const float* __restrict__ g0,
                                                         const float* __restrict__ bt0,
                                                         const float* __restrict__ w1g,
                                                         const float* __restrict__ w2g,
                                                         short* __restrict__ wf1,
                                                         float* __restrict__ c1,
                                                         short* __restrict__ wf2r,
                                                         short* __restrict__ wf3r)
{
    const int tid = threadIdx.x;
    if (tid < 512) {
        const int f = tid >> 6, l = tid & 63;
        const int o = (f >> 1) * 16 + (l & 15);
        const int kb = (f & 1) * 32 + (l >> 4) * 8;
#pragma unroll
        for (int j = 0; j < 8; ++j)
            wf2r[tid * 8 + j] = (short)f2bf(w1g[o * 64 + kb + j]);
    }
    {
        const int f = tid >> 6, l = tid & 63;
        const int o = (f >> 1) * 16 + (l & 15);
        const int kb = (f & 1) * 32 + (l >> 4) * 8;
#pragma unroll
        for (int j = 0; j < 8; ++j)
            wf3r[tid * 8 + j] = (short)f2bf(w2g[o * 64 + kb + j]);
    }

    __shared__ double red[672];
    __shared__ double tot[42];
    __shared__ float Asf[64];
    if (tid < 672) {
        const int j = tid % 42, r = tid / 42;   // 16 reducers per moment
        double s = 0.0;
#pragma unroll
        for (int i = r; i < 64; i += 16) s += (double)red64[(size_t)i * 42 + j];
        red[tid] = s;
    }
    __syncthreads();
    if (tid < 42) {
        double s = 0.0;
        for (int r = 0; r < 16; ++r) s += red[r * 42 + tid];
        tot[tid] = s / (double)MTOT;
    }
    __syncthreads();
    if (tid < 64) {
        double m1 = 0.0;
        for (int c = 0; c < 6; ++c) m1 += (double)w0[tid * 6 + c] * tot[c];
        double e2 = 0.0;
        for (int c = 0; c < 6; ++c)
            for (int d = 0; d < 6; ++d)
                e2 += (double)w0[tid * 6 + c] * (double)w0[tid * 6 + d] * tot[6 + c * 6 + d];
        double var = e2 - m1 * m1;
        if (var < 0.0) var = 0.0;
        const double A = (double)g0[tid] / sqrt(var + 1e-5);
        Asf[tid] = (float)A;
        c1[tid] = (float)((double)bt0[tid] - A * m1);
    }
    __syncthreads();
    if (tid < 256) {
        const int l = tid & 63;
        const int o = (tid >> 6) * 16 + (l & 15);
        const int h = l >> 4;
#pragma unroll
        for (int j = 0; j < 8; ++j) {
            const float val = (h == 0 && j < 6) ? Asf[o] * w0[o * 6 + j] : 0.f;
            wf1[tid * 8 + j] = (short)f2bf(val);
        }
    }
}

// ---------------------------------------------------------------------------
// MFMA chain kernel. Stats 16-lane reduce now via DPP rotate-add (VALU)
// instead of shfl_xor (LDS pipe). Otherwise round-8 verbatim.
// PHASE 2: stats of x2_nb. PHASE 3: stats of x3_nb + pre-BN3 group max.
// ---------------------------------------------------------------------------
template<int PHASE>
__global__ __launch_bounds__(256, 2) void chain_kernel(
    const float* __restrict__ v,
    const short* __restrict__ wf1, const float* __restrict__ c1,
    const short* __restrict__ wf2, const float* __restrict__ c2,
    const short* __restrict__ wf3,
    float* __restrict__ part, float* __restrict__ gmax, int tpb)
{
    __shared__ alignas(16) unsigned Hu1[4][16][36];
    __shared__ alignas(16) unsigned Hu2[(PHASE == 3) ? 4 : 1][16][36];
    __shared__ alignas(16) short w3l[(PHASE == 3) ? 8192 : 8];
    __shared__ alignas(16) float gm[(PHASE == 3) ? 4 : 1][128][20];
    __shared__ float redf[4][4][64];

    const int tid = threadIdx.x;
    const int w = tid >> 6, l = tid & 63;
    const int mcol = l & 15, h = l >> 4;

    if constexpr (PHASE == 3) {
        const unsigned* src = (const unsigned*)wf3;
        unsigned* dst = (unsigned*)w3l;
        for (int i = tid; i < 4096; i += 256) dst[i] = src[i];
    }
    __syncthreads();

    bfrag a1[4];
#pragma unroll
    for (int t = 0; t < 4; ++t) a1[t] = *(const bfrag*)&wf1[(t * 64 + l) * 8];
    bfrag a2[8];
#pragma unroll
    for (int f = 0; f < 8; ++f) a2[f] = *(const bfrag*)&wf2[(f * 64 + l) * 8];
    float c1v[16];
#pragma unroll
    for (int t = 0; t < 4; ++t)
#pragma unroll
        for (int r = 0; r < 4; ++r) c1v[t * 4 + r] = c1[t * 16 + h * 4 + r];
    float c2v[16];
    if constexpr (PHASE == 3) {
#pragma unroll
        for (int t = 0; t < 4; ++t)
#pragma unroll
            for (int r = 0; r < 4; ++r) c2v[t * 4 + r] = c2[t * 16 + h * 4 + r];
    }

    constexpr int NS = (PHASE == 3) ? 32 : 16;
    float sA[NS], qA[NS];
#pragma unroll
    for (int i = 0; i < NS; ++i) { sA[i] = 0.f; qA[i] = 0.f; }

    const facc zf = {0.f, 0.f, 0.f, 0.f};

    for (int ti = 0; ti < tpb; ++ti) {
        const int tile = blockIdx.x * tpb + ti;
        float mx[(PHASE == 3) ? 32 : 1];
        if constexpr (PHASE == 3) {
#pragma unroll
            for (int i = 0; i < 32; ++i) mx[i] = -3.0e38f;
        }

#pragma unroll
        for (int st = 0; st < 2; ++st) {
            const int mg = tile * 128 + w * 32 + st * 16 + mcol;

            bfrag bv;
#pragma unroll
            for (int j = 0; j < 8; ++j) bv[j] = 0;
            if (h == 0) {
#pragma unroll
                for (int j = 0; j < 6; ++j)
                    bv[j] = (short)f2bf(v[(size_t)j * MTOT + mg]);
            }
            facc x1[4];
#pragma unroll
            for (int t = 0; t < 4; ++t) x1[t] = MFMA16(a1[t], bv, zf);
#pragma unroll
            for (int t = 0; t < 4; ++t)
#pragma unroll
                for (int rr = 0; rr < 2; ++rr)
                    Hu1[w][mcol][t * 8 + h * 2 + rr] = packbf(
                        fmaxf(x1[t][2 * rr]     + c1v[t * 4 + 2 * rr],     0.f),
                        fmaxf(x1[t][2 * rr + 1] + c1v[t * 4 + 2 * rr + 1], 0.f));

            const bfrag b0 = *(const bfrag*)&Hu1[w][mcol][h * 4];
            const bfrag b1 = *(const bfrag*)&Hu1[w][mcol][16 + h * 4];

            if constexpr (PHASE == 2) {
#pragma unroll
                for (int t = 0; t < 4; ++t) {
                    facc a = MFMA16(a2[2 * t], b0, zf);
                    a = MFMA16(a2[2 * t + 1], b1, a);
#pragma unroll
                    for (int r = 0; r < 4; ++r) {
                        const float x = a[r];
                        sA[t * 4 + r] += x;
                        qA[t * 4 + r] = fmaf(x, x, qA[t * 4 + r]);
                    }
                }
            } else {
#pragma unroll
                for (int t = 0; t < 4; ++t) {
                    facc a = MFMA16(a2[2 * t], b0, zf);
                    a = MFMA16(a2[2 * t + 1], b1, a);
#pragma unroll
                    for (int rr = 0; rr < 2; ++rr)
                        Hu2[w][mcol][t * 8 + h * 2 + rr] = packbf(
                            fmaxf(a[2 * rr]     + c2v[t * 4 + 2 * rr],     0.f),
                            fmaxf(a[2 * rr + 1] + c2v[t * 4 + 2 * rr + 1], 0.f));
                }
                const bfrag d0 = *(const bfrag*)&Hu2[w][mcol][h * 4];
                const bfrag d1 = *(const bfrag*)&Hu2[w][mcol][16 + h * 4];
#pragma unroll
                for (int t3 = 0; t3 < 8; ++t3) {
                    const bfrag wa = *(const bfrag*)&w3l[((t3 * 2 + 0) * 64 + l) * 8];
                    const bfrag wb = *(const bfrag*)&w3l[((t3 * 2 + 1) * 64 + l) * 8];
                    facc a = MFMA16(wa, d0, zf);
                    a = MFMA16(wb, d1, a);
#pragma unroll
                    for (int r = 0; r < 4; ++r) {
                        const float x = a[r];
                        const int i = t3 * 4 + r;
                        sA[i] += x;
                        qA[i] = fmaf(x, x, qA[i]);
                        mx[i] = fmaxf(mx[i], x);
                    }
                }
            }
        }

        if constexpr (PHASE == 3) {
#pragma unroll
            for (int t3 = 0; t3 < 8; ++t3)
#pragma unroll
                for (int r = 0; r < 4; ++r)
                    gm[w][t3 * 16 + h * 4 + r][mcol] = mx[t3 * 4 + r];
            float m0 = -3.0e38f, m1 = -3.0e38f;
#pragma unroll
            for (int c4i = 0; c4i < 4; ++c4i) {
                const facc v0 = *(const facc*)&gm[w][2 * l][c4i * 4];
                const facc v1 = *(const facc*)&gm[w][2 * l + 1][c4i * 4];
#pragma unroll
                for (int jj = 0; jj < 4; ++jj) {
                    m0 = fmaxf(m0, v0[jj]);
                    m1 = fmaxf(m1, v1[jj]);
                }
            }
            const int g = tile * 4 + w;
            gmax[(size_t)g * 128 + 2 * l]     = m0;
            gmax[(size_t)g * 128 + 2 * l + 1] = m1;
        }
    }

    // 16-lane-group stats reduce via DPP rotate-add (VALU pipe)
#pragma unroll
    for (int i = 0; i < NS; ++i) {
        sA[i] = dppadd16(sA[i]);
        qA[i] = dppadd16(qA[i]);
    }
    __syncthreads();
    if (mcol == 0) {
#pragma unroll
        for (int i = 0; i < NS; ++i) {
            redf[w][h][i] = sA[i];
            redf[w][h][NS + i] = qA[i];
        }
    }
    __syncthreads();
    if constexpr (PHASE == 2) {
        if (tid < 128) {
            const int o = tid & 63, sq = tid >> 6;
            const int i = (o >> 4) * 4 + (o & 3), hh = (o >> 2) & 3;
            const int idx = sq * 16 + i;
            const float s = redf[0][hh][idx] + redf[1][hh][idx] +
                            redf[2][hh][idx] + redf[3][hh][idx];
            part[(size_t)blockIdx.x * 128 + sq * 64 + o] = s;
        }
    } else {
        if (tid < 256) {
            const int o = tid & 127, sq = tid >> 7;
            const int i = (o >> 4) * 4 + (o & 3), hh = (o >> 2) & 3;
            const int idx = sq * 32 + i;
            const float s = redf[0][hh][idx] + redf[1][hh][idx] +
                            redf[2][hh][idx] + redf[3][hh][idx];
            part[(size_t)blockIdx.x * 256 + sq * 128 + o] = s;
        }
    }
}

// ---------------------------------------------------------------------------
// finalize2 (1024 thr, 8 reducers/stat, unroll-4): chain<2> partials
// (2048 x [s64|q64]) -> A2/c2; emit folded bf16 W2 A-frags.
// ---------------------------------------------------------------------------
__global__ __launch_bounds__(1024) void finalize2_kernel(const float* __restrict__ part,
                                                         const float* __restrict__ w1g,
                                                         const float* __restrict__ g1,
                                                         const float* __restrict__ bt1,
                                                         short* __restrict__ wf2f,
                                                         float* __restrict__ c2)
{
    __shared__ double tot[1024];
    __shared__ float As[64];
    const int tid = threadIdx.x;
    const int j = tid & 127, r = tid >> 7;    // 8 reducers per stat
    double s = 0.0;
#pragma unroll 4
    for (int blk = r; blk < 2048; blk += 8) s += (double)part[(size_t)blk * 128 + j];
    tot[tid] = s;
    __syncthreads();
    if (tid < 128) {
        double t = 0.0;
#pragma unroll
        for (int g = 0; g < 8; ++g) t += tot[g * 128 + tid];
        tot[tid] = t;
    }
    __syncthreads();
    if (tid < 64) {
        const double mean = tot[tid] / (double)MTOT;
        double var = tot[64 + tid] / (double)MTOT - mean * mean;
        if (var < 0.0) var = 0.0;
        const double A = (double)g1[tid] / sqrt(var + 1e-5);
        As[tid] = (float)A;
        c2[tid] = (float)((double)bt1[tid] - A * mean);
    }
    __syncthreads();
    if (tid < 512) {
        const int f = tid >> 6, l = tid & 63;
        const int o = (f >> 1) * 16 + (l & 15);
        const int kb = (f & 1) * 32 + (l >> 4) * 8;
#pragma unroll
        for (int j8 = 0; j8 < 8; ++j8)
            wf2f[tid * 8 + j8] = (short)f2bf(As[o] * w1g[o * 64 + kb + j8]);
    }
}

// ---------------------------------------------------------------------------
// finalize3 (1024 thr, 4 reducers/stat, unroll-4): chain<3> partials
// (2048 x [s128|q128]) -> A3/c3.
// ---------------------------------------------------------------------------
__global__ __launch_bounds__(1024) void finalize3_kernel(const float* __restrict__ part,
                                                         const float* __restrict__ g2,
                                                         const float* __restrict__ bt2,
                                                         float* __restrict__ A3,
                                                         float* __restrict__ c3)
{
    __shared__ double tot[1024];
    const int tid = threadIdx.x;
    const int j = tid & 255, r = tid >> 8;    // 4 reducers per stat
    double s = 0.0;
#pragma unroll 4
    for (int blk = r; blk < 2048; blk += 4) s += (double)part[(size_t)blk * 256 + j];
    tot[tid] = s;
    __syncthreads();
    if (tid < 256) {
        const double t = tot[tid] + tot[256 + tid] + tot[512 + tid] + tot[768 + tid];
        tot[tid] = t;
    }
    __syncthreads();
    if (tid < 128) {
        const double mean = tot[tid] / (double)MTOT;
        double var = tot[128 + tid] / (double)MTOT - mean * mean;
        if (var < 0.0) var = 0.0;
        const double A = (double)g2[tid] / sqrt(var + 1e-5);
        A3[tid] = (float)A;
        c3[tid] = (float)((double)bt2[tid] - A * mean);
    }
}

// ---------------------------------------------------------------------------
// final_out: in-place out = relu(A3*gmax + c3) over (16384 groups x 128 ch).
// ---------------------------------------------------------------------------
__global__ __launch_bounds__(256) void final_out_kernel(float* __restrict__ outF,
                                                        const float* __restrict__ A3,
                                                        const float* __restrict__ c3)
{
    __shared__ float As[128], Cs[128];
    const int tid = threadIdx.x;
    if (tid < 128) { As[tid] = A3[tid]; Cs[tid] = c3[tid]; }
    __syncthreads();
    const int idx = (int)blockIdx.x * 256 + tid;      // f4 index, total 524288
    f4 val = *reinterpret_cast<f4*>(&outF[(size_t)idx * 4]);
    const int chb = (idx * 4) & 127;
#pragma unroll
    for (int jj = 0; jj < 4; ++jj)
        val.v[jj] = fmaxf(fmaf(As[chb + jj], val.v[jj], Cs[chb + jj]), 0.f);
    *reinterpret_cast<f4*>(&outF[(size_t)idx * 4]) = val;
}

// ---------------------------------------------------------------------------
extern "C" void kernel_launch(void* const* d_in, const int* in_sizes, int n_in,
                              void* d_out, int out_size, void* d_ws, size_t ws_size,
                              hipStream_t stream)
{
    const float* xyz  = (const float*)d_in[0];
    const float* feat = (const float*)d_in[1];
    const float* w0  = (const float*)d_in[2];
    const float* g0  = (const float*)d_in[4];
    const float* bt0 = (const float*)d_in[5];
    const float* w1  = (const float*)d_in[6];
    const float* g1  = (const float*)d_in[8];
    const float* bt1 = (const float*)d_in[9];
    const float* w2  = (const float*)d_in[10];
    const float* g2  = (const float*)d_in[12];
    const float* bt2 = (const float*)d_in[13];

    float* out    = (float*)d_out;
    float* newxyz = out;                 // (16,1024,3)
    float* outF   = out + BB * SS * 3;   // (16,1024,128) — gmax then final

    float* wsf   = (float*)d_ws;
    float* v     = wsf;                        // 3145728 floats
    float* part  = wsf + 6ull * MTOT;          // 688128 (moments / stat partials)
    float* red64 = part + 688128;              // 64*42 = 2688
    float* c1    = red64 + 2688;               // 64
    float* c2    = c1 + 64;                    // 64
    float* A3    = c2 + 64;                    // 128
    float* c3    = A3 + 128;                   // 128
    short* wf1   = (short*)(c3 + 128);         // 2048 shorts (4 frags)
    short* wf2r  = wf1 + 2048;                 // 4096 shorts (8 frags, raw)
    short* wf2f  = wf2r + 4096;                // 4096 shorts (8 frags, folded)
    short* wf3   = wf2f + 4096;                // 8192 shorts (16 frags, raw)

    fps_kernel<<<dim3(BB), dim3(256), 0, stream>>>(xyz, newxyz);
    ball_gather_kernel<<<dim3(4096), dim3(256), 0, stream>>>(xyz, feat, newxyz, v, part);
    reduce1_kernel<<<dim3(64), dim3(256), 0, stream>>>(part, red64);
    finalize1_kernel<<<dim3(1), dim3(1024), 0, stream>>>(red64, w0, g0, bt0, w1, w2,
                                                         wf1, c1, wf2r, wf3);

    chain_kernel<2><<<dim3(2048), dim3(256), 0, stream>>>(v, wf1, c1, wf2r, nullptr,
                                                          nullptr, part, nullptr, 2);
    finalize2_kernel<<<dim3(1), dim3(1024), 0, stream>>>(part, w1, g1, bt1, wf2f, c2);

    chain_kernel<3><<<dim3(2048), dim3(256), 0, stream>>>(v, wf1, c1, wf2f, c2,
                                                          wf3, part, outF, 2);
    finalize3_kernel<<<dim3(1), dim3(1024), 0, stream>>>(part, g2, bt2, A3, c3);
    final_out_kernel<<<dim3(2048), dim3(256), 0, stream>>>(outF, A3, c3);
}

// Round 12
// 1151.738 us; speedup vs baseline: 4.1286x; 1.0660x over previous
//
#include <hip/hip_runtime.h>
#include <math.h>

// Problem constants
#define BB 16
#define NN 8192
#define SS 1024
#define GG 32
#define MTOT (BB*SS*GG)   // 524288
// MLP: 6 -> 64 -> 64 -> 128

struct alignas(16) f4 { float v[4]; };

typedef __attribute__((ext_vector_type(8))) short bfrag;   // 8 bf16 = 4 VGPR
typedef __attribute__((ext_vector_type(4))) float facc;    // 4 f32 acc

#define MFMA16(a, b, c) __builtin_amdgcn_mfma_f32_16x16x32_bf16(a, b, c, 0, 0, 0)

__device__ __forceinline__ unsigned short f2bf(float f) {
    const unsigned u = __float_as_uint(f);
    return (unsigned short)((u + 0x7FFFu + ((u >> 16) & 1u)) >> 16);
}
__device__ __forceinline__ unsigned packbf(float lo, float hi) {
    return (unsigned)f2bf(lo) | ((unsigned)f2bf(hi) << 16);
}

template<int CTRL>
__device__ __forceinline__ int dppmov(int x) {
    return __builtin_amdgcn_update_dpp(x, x, CTRL, 0xF, 0xF, true);
}
// one u64 max-reduce level via DPP permutation of (hi,lo)
template<int CTRL>
__device__ __forceinline__ void dlevel(int& hi, int& lo) {
    const int oh = dppmov<CTRL>(hi);
    const int ol = dppmov<CTRL>(lo);
    const unsigned long long o =
        ((unsigned long long)(unsigned)oh << 32) | (unsigned)ol;
    const unsigned long long c =
        ((unsigned long long)(unsigned)hi << 32) | (unsigned)lo;
    if (o > c) { hi = oh; lo = ol; }
}
// 16-lane-group sum via ROW_ROR rotate-reduce (every lane gets group total)
__device__ __forceinline__ float dppadd16(float x) {
    x += __int_as_float(dppmov<0x121>(__float_as_int(x)));   // ROW_ROR:1
    x += __int_as_float(dppmov<0x122>(__float_as_int(x)));   // ROW_ROR:2
    x += __int_as_float(dppmov<0x124>(__float_as_int(x)));   // ROW_ROR:4
    x += __int_as_float(dppmov<0x128>(__float_as_int(x)));   // ROW_ROR:8
    return x;
}

// ---------------------------------------------------------------------------
// FPS — round-10 reduce shape verbatim (measured 916 us; round-11's LDS-slot
// flattening regressed +69 us — reverted). Scalar __f*_rn distance math ONLY
// (packed-f32 failed twice with identical wrong output — dead end).
// ---------------------------------------------------------------------------
__global__ __launch_bounds__(256) void fps_kernel(const float* __restrict__ xyz,
                                                  float* __restrict__ newxyz)
{
    __shared__ float lx[NN], ly[NN], lz[NN];            // 96 KB
    __shared__ unsigned long long slots[2][4];
    const int b = blockIdx.x;
    const int t = threadIdx.x;
    const int wave = t >> 6, lane = t & 63;
    const float* base = xyz + (size_t)b * NN * 3;

    float px[32], py[32], pz[32], dd[32];
#pragma unroll
    for (int k = 0; k < 32; ++k) {
        const int p = (k << 8) + t;
        const float x = base[p * 3 + 0];
        const float y = base[p * 3 + 1];
        const float z = base[p * 3 + 2];
        px[k] = x; py[k] = y; pz[k] = z; dd[k] = 1e10f;
        lx[p] = x; ly[p] = y; lz[p] = z;
    }
    __syncthreads();

    int far = 0;
    float* outb = newxyz + (size_t)b * SS * 3;
    for (int s = 0; s < SS; ++s) {
        const float cx = lx[far], cy = ly[far], cz = lz[far];
        if (t == 0) {
            outb[s * 3 + 0] = cx;
            outb[s * 3 + 1] = cy;
            outb[s * 3 + 2] = cz;
        }
        float bf = -1.f;
        unsigned binv = 0u;
#pragma unroll
        for (int k = 0; k < 32; ++k) {
            const float dx = __fsub_rn(px[k], cx);
            const float dy = __fsub_rn(py[k], cy);
            const float dz = __fsub_rn(pz[k], cz);
            const float d  = __fadd_rn(__fadd_rn(__fmul_rn(dx, dx), __fmul_rn(dy, dy)),
                                       __fmul_rn(dz, dz));
            const float nd = fminf(dd[k], d);
            dd[k] = nd;
            if (nd > bf) {                         // strict > keeps lowest k
                bf = nd;
                binv = 0xFFFFFFFFu - (unsigned)((k << 8) + t);
            }
        }

        int hi = __float_as_int(bf);   // bf >= 0 -> monotone bit pattern
        int lo = (int)binv;
        dlevel<0x121>(hi, lo);         // ROW_ROR:1
        dlevel<0x122>(hi, lo);         // ROW_ROR:2
        dlevel<0x124>(hi, lo);         // ROW_ROR:4
        dlevel<0x128>(hi, lo);         // ROW_ROR:8  -> max over each 16-row
        {
            const int oh = __shfl_xor(hi, 16), ol = __shfl_xor(lo, 16);
            const unsigned long long o =
                ((unsigned long long)(unsigned)oh << 32) | (unsigned)ol;
            const unsigned long long c =
                ((unsigned long long)(unsigned)hi << 32) | (unsigned)lo;
            if (o > c) { hi = oh; lo = ol; }
        }
        {
            const int oh = __shfl_xor(hi, 32), ol = __shfl_xor(lo, 32);
            const unsigned long long o =
                ((unsigned long long)(unsigned)oh << 32) | (unsigned)ol;
            const unsigned long long c =
                ((unsigned long long)(unsigned)hi << 32) | (unsigned)lo;
            if (o > c) { hi = oh; lo = ol; }
        }

        if (lane == 0)
            slots[s & 1][wave] =
                ((unsigned long long)(unsigned)hi << 32) | (unsigned)lo;
        __syncthreads();
        unsigned long long g = slots[s & 1][0];
#pragma unroll
        for (int w = 1; w < 4; ++w) {
            const unsigned long long o = slots[s & 1][w];
            g = (o > g) ? o : g;
        }
        far = (int)(0xFFFFFFFFu - (unsigned)(g & 0xFFFFFFFFull));
    }
}

// ---------------------------------------------------------------------------
// ball query + gather + v moments. 2-chunk unrolled scan: both chunks' loads
// issue back-to-back (2x memory-level parallelism vs the serial
// load->exit-check chain). Semantics identical: pos<GG guard drops overflow
// hits; cnt accounting exact; pad path unchanged.
// ---------------------------------------------------------------------------
__global__ __launch_bounds__(256) void ball_gather_kernel(const float* __restrict__ xyz,
                                                          const float* __restrict__ feat,
                                                          const float* __restrict__ newxyz,
                                                          float* __restrict__ v,
                                                          float* __restrict__ part1)
{
    const int wid  = (int)((blockIdx.x * 256 + threadIdx.x) >> 6);
    const int lane = threadIdx.x & 63;
    if (wid >= BB * SS) return;
    const int b = wid >> 10;

    const float cx = newxyz[wid * 3 + 0];
    const float cy = newxyz[wid * 3 + 1];
    const float cz = newxyz[wid * 3 + 2];
    const float* xb = xyz + (size_t)b * NN * 3;
    const float* fb = feat + (size_t)b * NN * 3;
    const size_t mbase = (size_t)wid * GG;

    float mS[6];
    float mP[36];
#pragma unroll
    for (int c = 0; c < 6; ++c) mS[c] = 0.f;
#pragma unroll
    for (int c = 0; c < 36; ++c) mP[c] = 0.f;

    int cnt = 0, firstp = -1;

    auto emit = [&](int p, float x, float y, float z, int pos) {
        const size_t mm = mbase + pos;
        float a[6];
        a[0] = __fsub_rn(x, cx);
        a[1] = __fsub_rn(y, cy);
        a[2] = __fsub_rn(z, cz);
        a[3] = fb[p * 3 + 0];
        a[4] = fb[p * 3 + 1];
        a[5] = fb[p * 3 + 2];
#pragma unroll
        for (int c = 0; c < 6; ++c) {
            v[(size_t)c * MTOT + mm] = a[c];
            mS[c] += a[c];
#pragma unroll
            for (int dch = 0; dch < 6; ++dch)
                mP[c * 6 + dch] = fmaf(a[c], a[dch], mP[c * 6 + dch]);
        }
    };

    for (int base = 0; base < NN && cnt < GG; base += 128) {
        const int pA = base + lane;
        const int pB = base + 64 + lane;
        // issue both chunks' loads up front (independent -> overlapped)
        const float xA = xb[pA * 3 + 0], yA = xb[pA * 3 + 1], zA = xb[pA * 3 + 2];
        const float xB = xb[pB * 3 + 0], yB = xb[pB * 3 + 1], zB = xb[pB * 3 + 2];

        const float dxA = __fsub_rn(cx, xA), dyA = __fsub_rn(cy, yA), dzA = __fsub_rn(cz, zA);
        const float dA  = __fadd_rn(__fadd_rn(__fmul_rn(dxA, dxA), __fmul_rn(dyA, dyA)),
                                    __fmul_rn(dzA, dzA));
        const float dxB = __fsub_rn(cx, xB), dyB = __fsub_rn(cy, yB), dzB = __fsub_rn(cz, zB);
        const float dB  = __fadd_rn(__fadd_rn(__fmul_rn(dxB, dxB), __fmul_rn(dyB, dyB)),
                                    __fmul_rn(dzB, dzB));

        const bool hitA = (dA <= 0.04f);
        const bool hitB = (dB <= 0.04f);
        const unsigned long long mA = __ballot(hitA);
        const unsigned long long mB = __ballot(hitB);

        if (firstp < 0) {
            if (mA != 0ull)      firstp = base + (int)__builtin_ctzll(mA);
            else if (mB != 0ull) firstp = base + 64 + (int)__builtin_ctzll(mB);
        }

        const int posA = cnt + (int)__popcll(mA & ((1ull << lane) - 1ull));
        if (hitA && posA < GG) emit(pA, xA, yA, zA, posA);
        const int cntA = cnt + (int)__popcll(mA);

        const int posB = cntA + (int)__popcll(mB & ((1ull << lane) - 1ull));
        if (hitB && posB < GG) emit(pB, xB, yB, zB, posB);
        cnt = cntA + (int)__popcll(mB);
    }
    if (cnt < GG) {
        const int p = firstp;
        const float x = xb[p * 3 + 0], y = xb[p * 3 + 1], z = xb[p * 3 + 2];
        float a[6];
        a[0] = __fsub_rn(x, cx);
        a[1] = __fsub_rn(y, cy);
        a[2] = __fsub_rn(z, cz);
        a[3] = fb[p * 3 + 0];
        a[4] = fb[p * 3 + 1];
        a[5] = fb[p * 3 + 2];
        for (int j = cnt + lane; j < GG; j += 64) {
            const size_t mm = mbase + j;
#pragma unroll
            for (int c = 0; c < 6; ++c) {
                v[(size_t)c * MTOT + mm] = a[c];
                mS[c] += a[c];
#pragma unroll
                for (int dch = 0; dch < 6; ++dch)
                    mP[c * 6 + dch] = fmaf(a[c], a[dch], mP[c * 6 + dch]);
            }
        }
    }
#pragma unroll
    for (int off = 1; off < 64; off <<= 1) {
#pragma unroll
        for (int c = 0; c < 6; ++c) mS[c] += __shfl_xor(mS[c], off);
#pragma unroll
        for (int c = 0; c < 36; ++c) mP[c] += __shfl_xor(mP[c], off);
    }
    if (lane == 0) {
        float* row = part1 + (size_t)wid * 42;
#pragma unroll
        for (int c = 0; c < 6; ++c) row[c] = mS[c];
#pragma unroll
        for (int c = 0; c < 36; ++c) row[6 + c] = mP[c];
    }
}

// ---------------------------------------------------------------------------
// reduce1: collapse part1 (16384 x 42) -> red64 (64 x 42). 64 blocks x 256.
// ---------------------------------------------------------------------------
__global__ __launch_bounds__(256) void reduce1_kernel(const float* __restrict__ part1,
                                                      float* __restrict__ red64)
{
    __shared__ float ldsT[42][260];
    const int tid = threadIdx.x;
    const int row = (int)blockIdx.x * 256 + tid;
    const float* rp = part1 + (size_t)row * 42;
    float r42[42];
#pragma unroll
    for (int i = 0; i < 21; ++i) {
        const float2 v2 = *reinterpret_cast<const float2*>(rp + 2 * i);
        r42[2 * i] = v2.x; r42[2 * i + 1] = v2.y;
    }
#pragma unroll
    for (int c = 0; c < 42; ++c) ldsT[c][tid] = r42[c];
    __syncthreads();
    if (tid < 168) {
        const int c = tid >> 2, r = tid & 3;
        float s = 0.f;
#pragma unroll
        for (int k = 0; k < 64; ++k) s += ldsT[c][r * 64 + k];
        ldsT[c][256 + r] = s;   // pad columns 256..259
    }
    __syncthreads();
    if (tid < 42)
        red64[(size_t)blockIdx.x * 42 + tid] =
            (ldsT[tid][256] + ldsT[tid][257]) + (ldsT[tid][258] + ldsT[tid][259]);
}

// ---------------------------------------------------------------------------
// finalize1 (+prep merged, 1024 thr): build raw bf16 W2/W3 A-frags; reduce
// red64 (64 x 42); analytic BN1; emit folded W1 frags + c1.
// ---------------------------------------------------------------------------
__global__ __launch_bounds__(1024) void finalize1_kernel(const float* __restrict__ red64,
                                                         const float* __restrict__ w0,
                                                         const float* __restrict__ g0,
                                                         const float* __restrict__ bt0,
                                                         const float* __restrict__ w1g,
                                                         const float* __restrict__ w2g,
                                                         short* __restrict__ wf1,
                                                         float* __restrict__ c1,
                                                         short* __restrict__ wf2r,
                                                         short* __restrict__ wf3r)
{
    const int tid = threadIdx.x;
    if (tid < 512) {
        const int f = tid >> 6, l = tid & 63;
        const int o = (f >> 1) * 16 + (l & 15);
        const int kb = (f & 1) * 32 + (l >> 4) * 8;
#pragma unroll
        for (int j = 0; j < 8; ++j)
            wf2r[tid * 8 + j] = (short)f2bf(w1g[o * 64 + kb + j]);
    }
    {
        const int f = tid >> 6, l = tid & 63;
        const int o = (f >> 1) * 16 + (l & 15);
        const int kb = (f & 1) * 32 + (l >> 4) * 8;
#pragma unroll
        for (int j = 0; j < 8; ++j)
            wf3r[tid * 8 + j] = (short)f2bf(w2g[o * 64 + kb + j]);
    }

    __shared__ double red[672];
    __shared__ double tot[42];
    __shared__ float Asf[64];
    if (tid < 672) {
        const int j = tid % 42, r = tid / 42;   // 16 reducers per moment
        double s = 0.0;
#pragma unroll
        for (int i = r; i < 64; i += 16) s += (double)red64[(size_t)i * 42 + j];
        red[tid] = s;
    }
    __syncthreads();
    if (tid < 42) {
        double s = 0.0;
        for (int r = 0; r < 16; ++r) s += red[r * 42 + tid];
        tot[tid] = s / (double)MTOT;
    }
    __syncthreads();
    if (tid < 64) {
        double m1 = 0.0;
        for (int c = 0; c < 6; ++c) m1 += (double)w0[tid * 6 + c] * tot[c];
        double e2 = 0.0;
        for (int c = 0; c < 6; ++c)
            for (int d = 0; d < 6; ++d)
                e2 += (double)w0[tid * 6 + c] * (double)w0[tid * 6 + d] * tot[6 + c * 6 + d];
        double var = e2 - m1 * m1;
        if (var < 0.0) var = 0.0;
        const double A = (double)g0[tid] / sqrt(var + 1e-5);
        Asf[tid] = (float)A;
        c1[tid] = (float)((double)bt0[tid] - A * m1);
    }
    __syncthreads();
    if (tid < 256) {
        const int l = tid & 63;
        const int o = (tid >> 6) * 16 + (l & 15);
        const int h = l >> 4;
#pragma unroll
        for (int j = 0; j < 8; ++j) {
            const float val = (h == 0 && j < 6) ? Asf[o] * w0[o * 6 + j] : 0.f;
            wf1[tid * 8 + j] = (short)f2bf(val);
        }
    }
}

// ---------------------------------------------------------------------------
// MFMA chain kernel (round-11 verbatim: DPP rotate-add stats reduce).
// PHASE 2: stats of x2_nb. PHASE 3: stats of x3_nb + pre-BN3 group max.
// ---------------------------------------------------------------------------
template<int PHASE>
__global__ __launch_bounds__(256, 2) void chain_kernel(
    const float* __restrict__ v,
    const short* __restrict__ wf1, const float* __restrict__ c1,
    const short* __restrict__ wf2, const float* __restrict__ c2,
    const short* __restrict__ wf3,
    float* __restrict__ part, float* __restrict__ gmax, int tpb)
{
    __shared__ alignas(16) unsigned Hu1[4][16][36];
    __shared__ alignas(16) unsigned Hu2[(PHASE == 3) ? 4 : 1][16][36];
    __shared__ alignas(16) short w3l[(PHASE == 3) ? 8192 : 8];
    __shared__ alignas(16) float gm[(PHASE == 3) ? 4 : 1][128][20];
    __shared__ float redf[4][4][64];

    const int tid = threadIdx.x;
    const int w = tid >> 6, l = tid & 63;
    const int mcol = l & 15, h = l >> 4;

    if constexpr (PHASE == 3) {
        const unsigned* src = (const unsigned*)wf3;
        unsigned* dst = (unsigned*)w3l;
        for (int i = tid; i < 4096; i += 256) dst[i] = src[i];
    }
    __syncthreads();

    bfrag a1[4];
#pragma unroll
    for (int t = 0; t < 4; ++t) a1[t] = *(const bfrag*)&wf1[(t * 64 + l) * 8];
    bfrag a2[8];
#pragma unroll
    for (int f = 0; f < 8; ++f) a2[f] = *(const bfrag*)&wf2[(f * 64 + l) * 8];
    float c1v[16];
#pragma unroll
    for (int t = 0; t < 4; ++t)
#pragma unroll
        for (int r = 0; r < 4; ++r) c1v[t * 4 + r] = c1[t * 16 + h * 4 + r];
    float c2v[16];
    if constexpr (PHASE == 3) {
#pragma unroll
        for (int t = 0; t < 4; ++t)
#pragma unroll
            for (int r = 0; r < 4; ++r) c2v[t * 4 + r] = c2[t * 16 + h * 4 + r];
    }

    constexpr int NS = (PHASE == 3) ? 32 : 16;
    float sA[NS], qA[NS];
#pragma unroll
    for (int i = 0; i < NS; ++i) { sA[i] = 0.f; qA[i] = 0.f; }

    const facc zf = {0.f, 0.f, 0.f, 0.f};

    for (int ti = 0; ti < tpb; ++ti) {
        const int tile = blockIdx.x * tpb + ti;
        float mx[(PHASE == 3) ? 32 : 1];
        if constexpr (PHASE == 3) {
#pragma unroll
            for (int i = 0; i < 32; ++i) mx[i] = -3.0e38f;
        }

#pragma unroll
        for (int st = 0; st < 2; ++st) {
            const int mg = tile * 128 + w * 32 + st * 16 + mcol;

            bfrag bv;
#pragma unroll
            for (int j = 0; j < 8; ++j) bv[j] = 0;
            if (h == 0) {
#pragma unroll
                for (int j = 0; j < 6; ++j)
                    bv[j] = (short)f2bf(v[(size_t)j * MTOT + mg]);
            }
            facc x1[4];
#pragma unroll
            for (int t = 0; t < 4; ++t) x1[t] = MFMA16(a1[t], bv, zf);
#pragma unroll
            for (int t = 0; t < 4; ++t)
#pragma unroll
                for (int rr = 0; rr < 2; ++rr)
                    Hu1[w][mcol][t * 8 + h * 2 + rr] = packbf(
                        fmaxf(x1[t][2 * rr]     + c1v[t * 4 + 2 * rr],     0.f),
                        fmaxf(x1[t][2 * rr + 1] + c1v[t * 4 + 2 * rr + 1], 0.f));

            const bfrag b0 = *(const bfrag*)&Hu1[w][mcol][h * 4];
            const bfrag b1 = *(const bfrag*)&Hu1[w][mcol][16 + h * 4];

            if constexpr (PHASE == 2) {
#pragma unroll
                for (int t = 0; t < 4; ++t) {
                    facc a = MFMA16(a2[2 * t], b0, zf);
                    a = MFMA16(a2[2 * t + 1], b1, a);
#pragma unroll
                    for (int r = 0; r < 4; ++r) {
                        const float x = a[r];
                        sA[t * 4 + r] += x;
                        qA[t * 4 + r] = fmaf(x, x, qA[t * 4 + r]);
                    }
                }
            } else {
#pragma unroll
                for (int t = 0; t < 4; ++t) {
                    facc a = MFMA16(a2[2 * t], b0, zf);
                    a = MFMA16(a2[2 * t + 1], b1, a);
#pragma unroll
                    for (int rr = 0; rr < 2; ++rr)
                        Hu2[w][mcol][t * 8 + h * 2 + rr] = packbf(
                            fmaxf(a[2 * rr]     + c2v[t * 4 + 2 * rr],     0.f),
                            fmaxf(a[2 * rr + 1] + c2v[t * 4 + 2 * rr + 1], 0.f));
                }
                const bfrag d0 = *(const bfrag*)&Hu2[w][mcol][h * 4];
                const bfrag d1 = *(const bfrag*)&Hu2[w][mcol][16 + h * 4];
#pragma unroll
                for (int t3 = 0; t3 < 8; ++t3) {
                    const bfrag wa = *(const bfrag*)&w3l[((t3 * 2 + 0) * 64 + l) * 8];
                    const bfrag wb = *(const bfrag*)&w3l[((t3 * 2 + 1) * 64 + l) * 8];
                    facc a = MFMA16(wa, d0, zf);
                    a = MFMA16(wb, d1, a);
#pragma unroll
                    for (int r = 0; r < 4; ++r) {
                        const float x = a[r];
                        const int i = t3 * 4 + r;
                        sA[i] += x;
                        qA[i] = fmaf(x, x, qA[i]);
                        mx[i] = fmaxf(mx[i], x);
                    }
                }
            }
        }

        if constexpr (PHASE == 3) {
#pragma unroll
            for (int t3 = 0; t3 < 8; ++t3)
#pragma unroll
                for (int r = 0; r < 4; ++r)
                    gm[w][t3 * 16 + h * 4 + r][mcol] = mx[t3 * 4 + r];
            float m0 = -3.0e38f, m1 = -3.0e38f;
#pragma unroll
            for (int c4i = 0; c4i < 4; ++c4i) {
                const facc v0 = *(const facc*)&gm[w][2 * l][c4i * 4];
                const facc v1 = *(const facc*)&gm[w][2 * l + 1][c4i * 4];
#pragma unroll
                for (int jj = 0; jj < 4; ++jj) {
                    m0 = fmaxf(m0, v0[jj]);
                    m1 = fmaxf(m1, v1[jj]);
                }
            }
            const int g = tile * 4 + w;
            gmax[(size_t)g * 128 + 2 * l]     = m0;
            gmax[(size_t)g * 128 + 2 * l + 1] = m1;
        }
    }

    // 16-lane-group stats reduce via DPP rotate-add (VALU pipe)
#pragma unroll
    for (int i = 0; i < NS; ++i) {
        sA[i] = dppadd16(sA[i]);
        qA[i] = dppadd16(qA[i]);
    }
    __syncthreads();
    if (mcol == 0) {
#pragma unroll
        for (int i = 0; i < NS; ++i) {
            redf[w][h][i] = sA[i];
            redf[w][h][NS + i] = qA[i];
        }
    }
    __syncthreads();
    if constexpr (PHASE == 2) {
        if (tid < 128) {
            const int o = tid & 63, sq = tid >> 6;
            const int i = (o >> 4) * 4 + (o & 3), hh = (o >> 2) & 3;
            const int idx = sq * 16 + i;
            const float s = redf[0][hh][idx] + redf[1][hh][idx] +
                            redf[2][hh][idx] + redf[3][hh][idx];
            part[(size_t)blockIdx.x * 128 + sq * 64 + o] = s;
        }
    } else {
        if (tid < 256) {
            const int o = tid & 127, sq = tid >> 7;
            const int i = (o >> 4) * 4 + (o & 3), hh = (o >> 2) & 3;
            const int idx = sq * 32 + i;
            const float s = redf[0][hh][idx] + redf[1][hh][idx] +
                            redf[2][hh][idx] + redf[3][hh][idx];
            part[(size_t)blockIdx.x * 256 + sq * 128 + o] = s;
        }
    }
}

// ---------------------------------------------------------------------------
// finalize2 (1024 thr, 8 reducers/stat, unroll-4): chain<2> partials
// (2048 x [s64|q64]) -> A2/c2; emit folded bf16 W2 A-frags.
// ---------------------------------------------------------------------------
__global__ __launch_bounds__(1024) void finalize2_kernel(const float* __restrict__ part,
                                                         const float* __restrict__ w1g,
                                                         const float* __restrict__ g1,
                                                         const float* __restrict__ bt1,
                                                         short* __restrict__ wf2f,
                                                         float* __restrict__ c2)
{
    __shared__ double tot[1024];
    __shared__ float As[64];
    const int tid = threadIdx.x;
    const int j = tid & 127, r = tid >> 7;    // 8 reducers per stat
    double s = 0.0;
#pragma unroll 4
    for (int blk = r; blk < 2048; blk += 8) s += (double)part[(size_t)blk * 128 + j];
    tot[tid] = s;
    __syncthreads();
    if (tid < 128) {
        double t = 0.0;
#pragma unroll
        for (int g = 0; g < 8; ++g) t += tot[g * 128 + tid];
        tot[tid] = t;
    }
    __syncthreads();
    if (tid < 64) {
        const double mean = tot[tid] / (double)MTOT;
        double var = tot[64 + tid] / (double)MTOT - mean * mean;
        if (var < 0.0) var = 0.0;
        const double A = (double)g1[tid] / sqrt(var + 1e-5);
        As[tid] = (float)A;
        c2[tid] = (float)((double)bt1[tid] - A * mean);
    }
    __syncthreads();
    if (tid < 512) {
        const int f = tid >> 6, l = tid & 63;
        const int o = (f >> 1) * 16 + (l & 15);
        const int kb = (f & 1) * 32 + (l >> 4) * 8;
#pragma unroll
        for (int j8 = 0; j8 < 8; ++j8)
            wf2f[tid * 8 + j8] = (short)f2bf(As[o] * w1g[o * 64 + kb + j8]);
    }
}

// ---------------------------------------------------------------------------
// finalize3 (1024 thr, 4 reducers/stat, unroll-4): chain<3> partials
// (2048 x [s128|q128]) -> A3/c3.
// ---------------------------------------------------------------------------
__global__ __launch_bounds__(1024) void finalize3_kernel(const float* __restrict__ part,
                                                         const float* __restrict__ g2,
                                                         const float* __restrict__ bt2,
                                                         float* __restrict__ A3,
                                                         float* __restrict__ c3)
{
    __shared__ double tot[1024];
    const int tid = threadIdx.x;
    const int j = tid & 255, r = tid >> 8;    // 4 reducers per stat
    double s = 0.0;
#pragma unroll 4
    for (int blk = r; blk < 2048; blk += 4) s += (double)part[(size_t)blk * 256 + j];
    tot[tid] = s;
    __syncthreads();
    if (tid < 256) {
        const double t = tot[tid] + tot[256 + tid] + tot[512 + tid] + tot[768 + tid];
        tot[tid] = t;
    }
    __syncthreads();
    if (tid < 128) {
        const double mean = tot[tid] / (double)MTOT;
        double var = tot[128 + tid] / (double)MTOT - mean * mean;
        if (var < 0.0) var = 0.0;
        const double A = (double)g2[tid] / sqrt(var + 1e-5);
        A3[tid] = (float)A;
        c3[tid] = (float)((double)bt2[tid] - A * mean);
    }
}

// ---------------------------------------------------------------------------
// final_out: in-place out = relu(A3*gmax + c3) over (16384 groups x 128 ch).
// ---------------------------------------------------------------------------
__global__ __launch_bounds__(256) void final_out_kernel(float* __restrict__ outF,
                                                        const float* __restrict__ A3,
                                                        const float* __restrict__ c3)
{
    __shared__ float As[128], Cs[128];
    const int tid = threadIdx.x;
    if (tid < 128) { As[tid] = A3[tid]; Cs[tid] = c3[tid]; }
    __syncthreads();
    const int idx = (int)blockIdx.x * 256 + tid;      // f4 index, total 524288
    f4 val = *reinterpret_cast<f4*>(&outF[(size_t)idx * 4]);
    const int chb = (idx * 4) & 127;
#pragma unroll
    for (int jj = 0; jj < 4; ++jj)
        val.v[jj] = fmaxf(fmaf(As[chb + jj], val.v[jj], Cs[chb + jj]), 0.f);
    *reinterpret_cast<f4*>(&outF[(size_t)idx * 4]) = val;
}

// ---------------------------------------------------------------------------
extern "C" void kernel_launch(void* const* d_in, const int* in_sizes, int n_in,
                              void* d_out, int out_size, void* d_ws, size_t ws_size,
                              hipStream_t stream)
{
    const float* xyz  = (const float*)d_in[0];
    const float* feat = (const float*)d_in[1];
    const float* w0  = (const float*)d_in[2];
    const float* g0  = (const float*)d_in[4];
    const float* bt0 = (const float*)d_in[5];
    const float* w1  = (const float*)d_in[6];
    const float* g1  = (const float*)d_in[8];
    const float* bt1 = (const float*)d_in[9];
    const float* w2  = (const float*)d_in[10];
    const float* g2  = (const float*)d_in[12];
    const float* bt2 = (const float*)d_in[13];

    float* out    = (float*)d_out;
    float* newxyz = out;                 // (16,1024,3)
    float* outF   = out + BB * SS * 3;   // (16,1024,128) — gmax then final

    float* wsf   = (float*)d_ws;
    float* v     = wsf;                        // 3145728 floats
    float* part  = wsf + 6ull * MTOT;          // 688128 (moments / stat partials)
    float* red64 = part + 688128;              // 64*42 = 2688
    float* c1    = red64 + 2688;               // 64
    float* c2    = c1 + 64;                    // 64
    float* A3    = c2 + 64;                    // 128
    float* c3    = A3 + 128;                   // 128
    short* wf1   = (short*)(c3 + 128);         // 2048 shorts (4 frags)
    short* wf2r  = wf1 + 2048;                 // 4096 shorts (8 frags, raw)
    short* wf2f  = wf2r + 4096;                // 4096 shorts (8 frags, folded)
    short* wf3   = wf2f + 4096;                // 8192 shorts (16 frags, raw)

    fps_kernel<<<dim3(BB), dim3(256), 0, stream>>>(xyz, newxyz);
    ball_gather_kernel<<<dim3(4096), dim3(256), 0, stream>>>(xyz, feat, newxyz, v, part);
    reduce1_kernel<<<dim3(64), dim3(256), 0, stream>>>(part, red64);
    finalize1_kernel<<<dim3(1), dim3(1024), 0, stream>>>(red64, w0, g0, bt0, w1, w2,
                                                         wf1, c1, wf2r, wf3);

    chain_kernel<2><<<dim3(2048), dim3(256), 0, stream>>>(v, wf1, c1, wf2r, nullptr,
                                                          nullptr, part, nullptr, 2);
    finalize2_kernel<<<dim3(1), dim3(1024), 0, stream>>>(part, w1, g1, bt1, wf2f, c2);

    chain_kernel<3><<<dim3(2048), dim3(256), 0, stream>>>(v, wf1, c1, wf2f, c2,
                                                          wf3, part, outF, 2);
    finalize3_kernel<<<dim3(1), dim3(1024), 0, stream>>>(part, g2, bt2, A3, c3);
    final_out_kernel<<<dim3(2048), dim3(256), 0, stream>>>(outF, A3, c3);
}